// Round 9
// baseline (436.940 us; speedup 1.0000x reference)
//
#include <hip/hip_runtime.h>
#include <math.h>

typedef unsigned short u16;
typedef __bf16 bf16x8 __attribute__((ext_vector_type(8)));
typedef float f32x4 __attribute__((ext_vector_type(4)));

#define NPACK  11264   // padded packed-pair count (88*128)
#define NVALID 10864   // 8256 + 2080 + 528
#define BASE1  8256
#define BASE2  10336

__device__ __forceinline__ u16 f2bf(float f) {
    unsigned u = __builtin_bit_cast(unsigned, f);
    u += 0x7FFFu + ((u >> 16) & 1u);
    return (u16)(u >> 16);
}
__device__ __forceinline__ float bf2f(u16 h) {
    return __builtin_bit_cast(float, ((unsigned)h) << 16);
}

#define GLOAD_LDS16(g, l)                                                     \
    __builtin_amdgcn_global_load_lds(                                         \
        (const __attribute__((address_space(1))) void*)(g),                   \
        (__attribute__((address_space(3))) void*)(l), 16, 0, 0)

// packed triangular index (u<=v), per segment
__device__ __forceinline__ int pk0(int a, int b) {
    int u = min(a, b), v = max(a, b);
    return u * 128 - (u * (u - 1)) / 2 + (v - u);
}
__device__ __forceinline__ int pk1(int a, int b) {
    int u = min(a, b), v = max(a, b);
    return BASE1 + u * 64 - (u * (u - 1)) / 2 + (v - u);
}
__device__ __forceinline__ int pk2(int a, int b) {
    int u = min(a, b), v = max(a, b);
    return BASE2 + u * 32 - (u * (u - 1)) / 2 + (v - u);
}

// ---------------------------------------------------------------- fused prep
// bid <  86    : uv table
// 86..1109     : transpose W1 (32x32 tiles, grid 32x32)
// 1110..1365   : transpose W2 (grid 8x32)
// 1366..2389   : convert W1
// 2390..2645   : convert W2
__device__ __forceinline__ void prep_transpose(const float* __restrict__ in, int C,
                                               u16* __restrict__ out, int ldOut,
                                               int bx, int by, int tid) {
    __shared__ float tile[32][33];
    int tr0 = by * 32, tc0 = bx * 32;
    int lr = tid >> 5, lc = tid & 31;
#pragma unroll
    for (int i = 0; i < 4; i++) {
        int rr = lr + i * 8;
        tile[rr][lc] = in[(size_t)(tr0 + rr) * C + tc0 + lc];
    }
    __syncthreads();
#pragma unroll
    for (int i = 0; i < 4; i++) {
        int rr = lr + i * 8;
        out[(size_t)(tc0 + rr) * ldOut + tr0 + lc] = f2bf(tile[lc][rr]);
    }
}
__device__ __forceinline__ void prep_convert(const float* __restrict__ in,
                                             u16* __restrict__ out, int i, int n4) {
    if (i >= n4) return;
    float4 v = ((const float4*)in)[i];
    union { u16 a[4]; unsigned long long q; } o;
    o.a[0] = f2bf(v.x); o.a[1] = f2bf(v.y); o.a[2] = f2bf(v.z); o.a[3] = f2bf(v.w);
    ((unsigned long long*)out)[i] = o.q;
}

__global__ __launch_bounds__(256) void k_prep(u16* __restrict__ tab,
                                              const float* __restrict__ W1,
                                              const float* __restrict__ W2,
                                              u16* __restrict__ W1b,
                                              u16* __restrict__ W1tb,
                                              u16* __restrict__ W2b,
                                              u16* __restrict__ W2tb) {
    int bid = blockIdx.x, tid = threadIdx.x;
    if (bid < 86) {
        int j = bid * 256 + tid;
        if (j < 16384) {
            int u = j >> 7, v = j & 127;
            if (v >= u) tab[pk0(u, v)] = (u16)((u << 7) | v);
        } else if (j < 20480) {
            int k = j - 16384, u = k >> 6, v = k & 63;
            if (v >= u) tab[pk1(u, v)] = (u16)((1 << 14) | (u << 7) | v);
        } else if (j < 21504) {
            int k = j - 20480, u = k >> 5, v = k & 31;
            if (v >= u) tab[pk2(u, v)] = (u16)((2 << 14) | (u << 7) | v);
        } else if (j < 21504 + (NPACK - NVALID)) {
            tab[NVALID + (j - 21504)] = 0xFFFFu;
        }
    } else if (bid < 1110) {
        int k = bid - 86;                       // grid 32x32
        prep_transpose(W1, 1024, W1tb, 1024, k & 31, k >> 5, tid);
    } else if (bid < 1366) {
        int k = bid - 1110;                     // grid 8x32
        prep_transpose(W2, 256, W2tb, 1024, k & 7, k >> 3, tid);
    } else if (bid < 2390) {
        prep_convert(W1, W1b, (bid - 1366) * 256 + tid, 1024 * 1024 / 4);
    } else {
        prep_convert(W2, W2b, (bid - 2390) * 256 + tid, 1024 * 256 / 4);
    }
}

// ---------------------------------------------------------------- packed weights
__global__ __launch_bounds__(256) void k_packw(const float* __restrict__ w0,
                                               const float* __restrict__ w1,
                                               const float* __restrict__ w2,
                                               const u16* __restrict__ tab,
                                               u16* __restrict__ Wsym,
                                               u16* __restrict__ Wt) {
    __shared__ u16 tile[32][258];
    __shared__ u16 te[32];
    int i0 = blockIdx.x * 32, h0 = blockIdx.y * 256, tid = threadIdx.x;
    if (tid < 32) te[tid] = tab[i0 + tid];
    __syncthreads();
    const float s1 = 0.57735026918962576f, s2 = 0.44721359549995794f;
    for (int il = 0; il < 32; il++) {
        unsigned e = te[il];
        float val = 0.f;
        if ((e >> 14) != 3) {
            int seg = e >> 14, u = (e >> 7) & 127, v = e & 127;
            const float* wb; int S; float sc;
            if (seg == 0)      { wb = w0; S = 128; sc = 1.f; }
            else if (seg == 1) { wb = w1; S = 64;  sc = s1; }
            else               { wb = w2; S = 32;  sc = s2; }
            val = sc * (wb[(size_t)(u * S + v) * 1024 + h0 + tid] +
                        wb[(size_t)(v * S + u) * 1024 + h0 + tid]);
        }
        u16 bv = f2bf(val);
        Wsym[(size_t)(i0 + il) * 1024 + h0 + tid] = bv;
        tile[il][tid] = bv;
    }
    __syncthreads();
    union { u16 a[32]; uint4 q[4]; } pk;
#pragma unroll
    for (int il = 0; il < 32; il++) pk.a[il] = tile[il][tid];
    uint4* dst = (uint4*)(Wt + (size_t)(h0 + tid) * NPACK + i0);
#pragma unroll
    for (int q = 0; q < 4; q++) dst[q] = pk.q[q];
}

// ---------------------------------------------------------------- packed features
__global__ __launch_bounds__(256) void k_features_pack(const float* __restrict__ t,
                                                       const u16* __restrict__ tab,
                                                       u16* __restrict__ P) {
    __shared__ u16 tab_s[NPACK];
    __shared__ float tr[480];
    int b = blockIdx.x, tid = threadIdx.x;
    for (int j = tid; j < NPACK / 8; j += 256)
        ((uint4*)tab_s)[j] = ((const uint4*)tab)[j];
    for (int j = tid; j < 480; j += 256) tr[j] = t[(size_t)b * 480 + j];
    __syncthreads();
    u16* row = P + (size_t)b * NPACK;
    for (int i = tid; i < NPACK; i += 256) {
        unsigned e = tab_s[i];
        float p = 0.f;
        if ((e >> 14) != 3) {
            int seg = e >> 14, u = (e >> 7) & 127, v = e & 127;
            if (seg == 0) p = tr[u] * tr[v];
            else if (seg == 1) {
                const float* x1 = tr + 128;
                p = x1[u*3]*x1[v*3] + x1[u*3+1]*x1[v*3+1] + x1[u*3+2]*x1[v*3+2];
            } else {
                const float* x2 = tr + 320;
#pragma unroll
                for (int m = 0; m < 5; m++) p += x2[u*5+m] * x2[v*5+m];
            }
            if (u == v) p *= 0.5f;
        }
        row[i] = f2bf(p);
    }
}

// ---------------------------------------------------------------- GEMM 128-tile (MLP sizes)
__global__ __launch_bounds__(256) void k_gemm2(const u16* __restrict__ A, int ldA,
                                               const u16* __restrict__ B, int ldB,
                                               int kLen, float scale,
                                               const float* __restrict__ bias,
                                               float* __restrict__ Cf,
                                               u16* __restrict__ Cb, int ldC,
                                               u16* __restrict__ Cpart, int Mtot,
                                               int swz) {
    __shared__ u16 As[2][128 * 32];
    __shared__ u16 Bs[2][128 * 32];
    const int tid = threadIdx.x;
    const int wave = tid >> 6, lane = tid & 63;
    const int wm = wave >> 1, wn = wave & 1;
    int nT, mT, z;
    if (swz == 1) {
        int L = blockIdx.x;
        z = L & 7; int r = L >> 3;
        nT = r >> 4; mT = r & 15;
    } else if (swz == 2) {
        int L = blockIdx.x;
        int c = L & 7, r = L >> 3;
        nT = (r % 11) * 8 + c; mT = r / 11; z = 0;
    } else {
        nT = blockIdx.x; mT = blockIdx.y; z = blockIdx.z;
    }
    const int m0 = mT * 128, n0 = nT * 128;
    const size_t kOff = (size_t)z * kLen;

    const int chl = (((lane & 3) ^ ((lane >> 3) & 3))) * 8;
    const u16* aG = A + (size_t)(m0 + wave * 32 + (lane >> 2)) * ldA + kOff + chl;
    const u16* bG = B + (size_t)(n0 + wave * 32 + (lane >> 2)) * ldB + kOff + chl;
    const size_t aS = (size_t)16 * ldA;
    const size_t bS = (size_t)16 * ldB;
    u16* aL0 = &As[0][(wave * 32) * 32];
    u16* aL1 = &As[0][(wave * 32 + 16) * 32];
    u16* aH0 = &As[1][(wave * 32) * 32];
    u16* aH1 = &As[1][(wave * 32 + 16) * 32];
    u16* bL0 = &Bs[0][(wave * 32) * 32];
    u16* bL1 = &Bs[0][(wave * 32 + 16) * 32];
    u16* bH0 = &Bs[1][(wave * 32) * 32];
    u16* bH1 = &Bs[1][(wave * 32 + 16) * 32];

    f32x4 acc[4][4];
#pragma unroll
    for (int i = 0; i < 4; i++)
#pragma unroll
        for (int j = 0; j < 4; j++) acc[i][j] = (f32x4){0.f, 0.f, 0.f, 0.f};

    const int ml = lane & 15, kq8 = lane >> 4;
    const int kqs = (kq8 ^ ((ml >> 1) & 3)) * 8;
    const u16* aRd0 = &As[0][(wm * 64 + ml) * 32 + kqs];
    const u16* bRd0 = &Bs[0][(wn * 64 + ml) * 32 + kqs];
    const u16* aRd1 = &As[1][(wm * 64 + ml) * 32 + kqs];
    const u16* bRd1 = &Bs[1][(wn * 64 + ml) * 32 + kqs];

    for (int k = 0; k < kLen; k += 64) {
        GLOAD_LDS16(aG, aL0);
        GLOAD_LDS16(aG + aS, aL1);
        GLOAD_LDS16(aG + 32, aH0);
        GLOAD_LDS16(aG + aS + 32, aH1);
        GLOAD_LDS16(bG, bL0);
        GLOAD_LDS16(bG + bS, bL1);
        GLOAD_LDS16(bG + 32, bH0);
        GLOAD_LDS16(bG + bS + 32, bH1);
        aG += 64; bG += 64;
        __syncthreads();
        {
            bf16x8 af[4], bfv[4];
#pragma unroll
            for (int i = 0; i < 4; i++) af[i]  = *(const bf16x8*)(aRd0 + i * 16 * 32);
#pragma unroll
            for (int j = 0; j < 4; j++) bfv[j] = *(const bf16x8*)(bRd0 + j * 16 * 32);
#pragma unroll
            for (int i = 0; i < 4; i++)
#pragma unroll
                for (int j = 0; j < 4; j++)
                    acc[i][j] = __builtin_amdgcn_mfma_f32_16x16x32_bf16(af[i], bfv[j], acc[i][j], 0, 0, 0);
        }
        {
            bf16x8 af[4], bfv[4];
#pragma unroll
            for (int i = 0; i < 4; i++) af[i]  = *(const bf16x8*)(aRd1 + i * 16 * 32);
#pragma unroll
            for (int j = 0; j < 4; j++) bfv[j] = *(const bf16x8*)(bRd1 + j * 16 * 32);
#pragma unroll
            for (int i = 0; i < 4; i++)
#pragma unroll
                for (int j = 0; j < 4; j++)
                    acc[i][j] = __builtin_amdgcn_mfma_f32_16x16x32_bf16(af[i], bfv[j], acc[i][j], 0, 0, 0);
        }
        __syncthreads();
    }

    const int q = lane >> 4, nl = lane & 15;
    if (Cpart) {
        u16* outP = Cpart + (size_t)z * Mtot * ldC;
#pragma unroll
        for (int i = 0; i < 4; i++)
#pragma unroll
            for (int j = 0; j < 4; j++)
#pragma unroll
                for (int reg = 0; reg < 4; reg++) {
                    int row = m0 + wm * 64 + i * 16 + q * 4 + reg;
                    int col = n0 + wn * 64 + j * 16 + nl;
                    outP[(size_t)row * ldC + col] = f2bf(acc[i][j][reg]);
                }
    } else {
#pragma unroll
        for (int i = 0; i < 4; i++)
#pragma unroll
            for (int j = 0; j < 4; j++)
#pragma unroll
                for (int reg = 0; reg < 4; reg++) {
                    int row = m0 + wm * 64 + i * 16 + q * 4 + reg;
                    int col = n0 + wn * 64 + j * 16 + nl;
                    float v = acc[i][j][reg] * scale + (bias ? bias[col] : 0.0f);
                    if (Cf) Cf[(size_t)row * ldC + col] = v;
                    else    Cb[(size_t)row * ldC + col] = f2bf(v);
                }
    }
}

// ---------------------------------------------------------------- GEMM 256-tile (GEMM1), R3 schedule
#define VMCNT0 asm volatile("s_waitcnt vmcnt(0)" ::: "memory")
#define VMCNT6 asm volatile("s_waitcnt vmcnt(6)" ::: "memory")
#define BARX() __builtin_amdgcn_s_barrier()

#define STG_A(p, kh, rh, kb) GLOAD_LDS16(aB + (size_t)(rh) * aH + (kb) + (kh) * 32, \
                                         &As[p][kh][((rh) * 128 + wave * 16) * 32])
#define STG_B(p, kh, rh, kb) GLOAD_LDS16(bB + (size_t)(rh) * bH + (kb) + (kh) * 32, \
                                         &Bs[p][kh][((rh) * 128 + wave * 16) * 32])
#define MMQ(fb, gb, bv) do { _Pragma("unroll") \
    for (int ff = 0; ff < 4; ff++) { _Pragma("unroll") \
        for (int gg = 0; gg < 2; gg++) { \
            acc[(fb)+ff][(gb)+gg] = __builtin_amdgcn_mfma_f32_16x16x32_bf16(a[2*ff],   bv[2*gg],   acc[(fb)+ff][(gb)+gg], 0, 0, 0); \
            acc[(fb)+ff][(gb)+gg] = __builtin_amdgcn_mfma_f32_16x16x32_bf16(a[2*ff+1], bv[2*gg+1], acc[(fb)+ff][(gb)+gg], 0, 0, 0); } } } while (0)

__global__ __launch_bounds__(512, 2) void k_gemm256(const u16* __restrict__ A, int ldA,
                                                    const u16* __restrict__ B, int ldB,
                                                    int kLen, float scale,
                                                    const float* __restrict__ bias,
                                                    u16* __restrict__ Cb, int ldC,
                                                    u16* __restrict__ Cpart, int Mtot,
                                                    int swz) {
    __shared__ __align__(16) u16 As[2][2][256 * 32];   // [buf][kh][row*32+k]  64 KB
    __shared__ __align__(16) u16 Bs[2][2][256 * 32];   // 64 KB
    const int tid = threadIdx.x;
    const int lane = tid & 63, wave = tid >> 6;
    const int wm = wave >> 2, wn = wave & 3;
    int mT, nT, z;
    if (swz == 1) {
        // GEMM1: 256 blocks. XCD = z = L&7. Within XCD: nT fastest.
        z = blockIdx.x & 7; int r = blockIdx.x >> 3; nT = r & 3; mT = r >> 2;
    } else {
        int x = blockIdx.x & 7, j = blockIdx.x >> 3;
        int nti = j >> 3; mT = j & 7;
        if (nti < 5)      nT = nti * 8 + x;
        else if (x < 4)   nT = 40 + x;
        else            { nT = 40 + (x - 4); mT = (j & 7) + 4; }
        z = 0;
    }
    const int m0 = mT * 256, n0 = nT * 256;
    const size_t kOff = (size_t)z * kLen;
    const int nTi = kLen >> 6;          // K-64 tiles, >= 2

    const int chl = ((tid & 3) ^ ((tid >> 3) & 3)) * 8;
    const u16* aB = A + (size_t)(m0 + (tid >> 2)) * ldA + kOff + chl;
    const u16* bB = B + (size_t)(n0 + (tid >> 2)) * ldB + kOff + chl;
    const size_t aH = (size_t)128 * ldA;
    const size_t bH = (size_t)128 * ldB;

    const int ml = lane & 15, kq8 = lane >> 4;
    const int kqs = (kq8 ^ ((ml >> 1) & 3)) * 8;
    const int aro = (wm * 128 + ml) * 32 + kqs;
    const int bro = (wn * 64 + ml) * 32 + kqs;

    f32x4 acc[8][4];
#pragma unroll
    for (int f = 0; f < 8; f++)
#pragma unroll
        for (int g = 0; g < 4; g++) acc[f][g] = (f32x4){0.f, 0.f, 0.f, 0.f};
    bf16x8 a[8], b[4], b2[4];

    STG_A(0, 0, 0, 0); STG_A(0, 0, 1, 0); STG_A(0, 1, 0, 0); STG_A(0, 1, 1, 0);
    STG_B(0, 0, 0, 0); STG_B(0, 0, 1, 0); STG_B(0, 1, 0, 0); STG_B(0, 1, 1, 0);
    VMCNT0;
    BARX();

    for (int t = 0; t < nTi; t++) {
        const int p = t & 1, p1 = p ^ 1;
        const int kb1 = (t + 1) << 6;
        const bool s1 = (t + 1) < nTi;
        // phase 0
#pragma unroll
        for (int f = 0; f < 4; f++) {
            a[2*f]   = *(const bf16x8*)&As[p][0][aro + f * 512];
            a[2*f+1] = *(const bf16x8*)&As[p][1][aro + f * 512];
        }
#pragma unroll
        for (int g = 0; g < 2; g++) {
            b[2*g]   = *(const bf16x8*)&Bs[p][0][bro + g * 512];
            b[2*g+1] = *(const bf16x8*)&Bs[p][1][bro + g * 512];
        }
        if (s1) { STG_A(p1, 0, 0, kb1); STG_A(p1, 0, 1, kb1); }
        BARX();
        __builtin_amdgcn_s_setprio(1);
        MMQ(0, 0, b);
        __builtin_amdgcn_s_setprio(0);
        BARX();
        // phase 1
#pragma unroll
        for (int g = 0; g < 2; g++) {
            b2[2*g]   = *(const bf16x8*)&Bs[p][0][bro + (g + 2) * 512];
            b2[2*g+1] = *(const bf16x8*)&Bs[p][1][bro + (g + 2) * 512];
        }
        if (s1) { STG_A(p1, 1, 0, kb1); STG_A(p1, 1, 1, kb1); }
        BARX();
        __builtin_amdgcn_s_setprio(1);
        MMQ(0, 2, b2);
        __builtin_amdgcn_s_setprio(0);
        BARX();
        // phase 2
#pragma unroll
        for (int f = 0; f < 4; f++) {
            a[2*f]   = *(const bf16x8*)&As[p][0][aro + (f + 4) * 512];
            a[2*f+1] = *(const bf16x8*)&As[p][1][aro + (f + 4) * 512];
        }
        if (s1) { STG_B(p1, 0, 0, kb1); STG_B(p1, 0, 1, kb1); }
        BARX();
        __builtin_amdgcn_s_setprio(1);
        MMQ(4, 0, b);
        __builtin_amdgcn_s_setprio(0);
        BARX();
        // phase 3
        if (s1) { STG_B(p1, 1, 0, kb1); STG_B(p1, 1, 1, kb1); }
        __builtin_amdgcn_s_setprio(1);
        MMQ(4, 2, b2);
        __builtin_amdgcn_s_setprio(0);
        if (s1) VMCNT0;
        BARX();
    }

    const int q = lane >> 4, nl = lane & 15;
    if (Cpart) {
        u16* outP = Cpart + (size_t)z * Mtot * ldC;
#pragma unroll
        for (int f = 0; f < 8; f++)
#pragma unroll
            for (int g = 0; g < 4; g++)
#pragma unroll
                for (int reg = 0; reg < 4; reg++) {
                    int row = m0 + wm * 128 + f * 16 + q * 4 + reg;
                    int col = n0 + wn * 64 + g * 16 + nl;
                    outP[(size_t)row * ldC + col] = f2bf(acc[f][g][reg]);
                }
    } else {
#pragma unroll
        for (int f = 0; f < 8; f++)
#pragma unroll
            for (int g = 0; g < 4; g++)
#pragma unroll
                for (int reg = 0; reg < 4; reg++) {
                    int row = m0 + wm * 128 + f * 16 + q * 4 + reg;
                    int col = n0 + wn * 64 + g * 16 + nl;
                    float v = acc[f][g][reg] * scale + (bias ? bias[col] : 0.0f);
                    Cb[(size_t)row * ldC + col] = f2bf(v);
                }
    }
}

// ---------------------------------------------------------------- GEMM 128x256-tile (GEMM2)
// R8 schedule + 3-buffer 2-deep pipeline (T4): tile t stages tile t+2 into
// buf (t+2)%3; boundary waits vmcnt(6) -> retires only t+1's 6 loads (issued
// a full tile earlier, certainly complete) while t+2's 6 stay in flight.
// Drain-to-zero removed from the steady-state loop (tail: vmcnt(0) once).
// LDS 144 KB (A 3x16 + B 3x32). Hazards: buf (t+2)%3 was last read by tile
// t-1, whose end barrier precedes these stage issues; tile t+2's loads are
// completion-checked at tile t+1's boundary vmcnt(6).
#define MMQ22(fb, gb, bv) do { _Pragma("unroll") \
    for (int ff = 0; ff < 2; ff++) { _Pragma("unroll") \
        for (int gg = 0; gg < 2; gg++) { \
            acc[(fb)+ff][(gb)+gg] = __builtin_amdgcn_mfma_f32_16x16x32_bf16(a[2*ff],   bv[2*gg],   acc[(fb)+ff][(gb)+gg], 0, 0, 0); \
            acc[(fb)+ff][(gb)+gg] = __builtin_amdgcn_mfma_f32_16x16x32_bf16(a[2*ff+1], bv[2*gg+1], acc[(fb)+ff][(gb)+gg], 0, 0, 0); } } } while (0)

__global__ __launch_bounds__(512, 2) void k_gemm128n(const u16* __restrict__ A, int ldA,
                                                     const u16* __restrict__ B, int ldB,
                                                     int kLen, float scale,
                                                     u16* __restrict__ Cb, int ldC) {
    __shared__ __align__(16) u16 As[3][2][128 * 32];   // 48 KB
    __shared__ __align__(16) u16 Bs[3][2][256 * 32];   // 96 KB
    const int tid = threadIdx.x;
    const int lane = tid & 63, wave = tid >> 6;
    const int wm = wave >> 2, wn = wave & 3;           // wm 0..1, wn 0..3
    int x = blockIdx.x & 7, j = blockIdx.x >> 3;
    int nti = j >> 4, mT = j & 15, nT;
    if (nti < 5) nT = nti * 8 + x;
    else { nT = 40 + (x & 3); mT = (j & 7) + 8 * (x >> 2); }
    const int m0 = mT * 128, n0 = nT * 256;
    const int nTi = kLen >> 6;

    const int chl = ((tid & 3) ^ ((tid >> 3) & 3)) * 8;
    const u16* aB = A + (size_t)(m0 + (tid >> 2)) * ldA + chl;   // rows 0..127
    const u16* bB = B + (size_t)(n0 + (tid >> 2)) * ldB + chl;
    const size_t bH = (size_t)128 * ldB;

    const int ml = lane & 15, kq8 = lane >> 4;
    const int kqs = (kq8 ^ ((ml >> 1) & 3)) * 8;
    const int aro = (wm * 64 + ml) * 32 + kqs;
    const int bro = (wn * 64 + ml) * 32 + kqs;

    f32x4 acc[4][4];
#pragma unroll
    for (int f = 0; f < 4; f++)
#pragma unroll
        for (int g = 0; g < 4; g++) acc[f][g] = (f32x4){0.f, 0.f, 0.f, 0.f};
    bf16x8 a[4], b[4], b2[4];

#define SG_A(p, kh, kb) GLOAD_LDS16(aB + (kb) + (kh) * 32, &As[p][kh][(wave * 16) * 32])
#define SG_B(p, kh, rh, kb) GLOAD_LDS16(bB + (size_t)(rh) * bH + (kb) + (kh) * 32, \
                                        &Bs[p][kh][((rh) * 128 + wave * 16) * 32])

    // prologue: stage T0 -> buf0 (6) and T1 -> buf1 (6); retire T0; barrier.
    SG_A(0, 0, 0); SG_A(0, 1, 0);
    SG_B(0, 0, 0, 0); SG_B(0, 0, 1, 0); SG_B(0, 1, 0, 0); SG_B(0, 1, 1, 0);
    if (nTi > 1) {
        SG_A(1, 0, 64); SG_A(1, 1, 64);
        SG_B(1, 0, 0, 64); SG_B(1, 0, 1, 64); SG_B(1, 1, 0, 64); SG_B(1, 1, 1, 64);
        VMCNT6;
    } else {
        VMCNT0;
    }
    BARX();

    int p = 0;
    for (int t = 0; t < nTi; t++) {
        const int p2 = (p >= 1) ? p - 1 : 2;           // (t+2) % 3
        const int kb2 = (t + 2) << 6;
        const bool s2 = (t + 2) < nTi;
        const bool s1 = (t + 1) < nTi;
        // phase 0: a f0..1, b g0..1; stage t+2 A kh0+kh1
#pragma unroll
        for (int f = 0; f < 2; f++) {
            a[2*f]   = *(const bf16x8*)&As[p][0][aro + f * 512];
            a[2*f+1] = *(const bf16x8*)&As[p][1][aro + f * 512];
        }
#pragma unroll
        for (int g = 0; g < 2; g++) {
            b[2*g]   = *(const bf16x8*)&Bs[p][0][bro + g * 512];
            b[2*g+1] = *(const bf16x8*)&Bs[p][1][bro + g * 512];
        }
        if (s2) { SG_A(p2, 0, kb2); SG_A(p2, 1, kb2); }
        BARX();
        __builtin_amdgcn_s_setprio(1);
        MMQ22(0, 0, b);
        __builtin_amdgcn_s_setprio(0);
        BARX();
        // phase 1: b2 g2..3; stage t+2 B kh0
#pragma unroll
        for (int g = 0; g < 2; g++) {
            b2[2*g]   = *(const bf16x8*)&Bs[p][0][bro + (g + 2) * 512];
            b2[2*g+1] = *(const bf16x8*)&Bs[p][1][bro + (g + 2) * 512];
        }
        if (s2) { SG_B(p2, 0, 0, kb2); SG_B(p2, 0, 1, kb2); }
        BARX();
        __builtin_amdgcn_s_setprio(1);
        MMQ22(0, 2, b2);
        __builtin_amdgcn_s_setprio(0);
        BARX();
        // phase 2: a f2..3; stage t+2 B kh1
#pragma unroll
        for (int f = 0; f < 2; f++) {
            a[2*f]   = *(const bf16x8*)&As[p][0][aro + (f + 2) * 512];
            a[2*f+1] = *(const bf16x8*)&As[p][1][aro + (f + 2) * 512];
        }
        if (s2) { SG_B(p2, 1, 0, kb2); SG_B(p2, 1, 1, kb2); }
        BARX();
        __builtin_amdgcn_s_setprio(1);
        MMQ22(2, 0, b);
        __builtin_amdgcn_s_setprio(0);
        BARX();
        // phase 3: no reads/stages; counted boundary wait
        __builtin_amdgcn_s_setprio(1);
        MMQ22(2, 2, b2);
        __builtin_amdgcn_s_setprio(0);
        if (s2)      { VMCNT6; }   // retire t+1's 6 (old); t+2's 6 stay in flight
        else if (s1) { VMCNT0; }   // tail: only t+1's (old) loads outstanding
        BARX();
        p = (p == 2) ? 0 : p + 1;
    }

    const int q = lane >> 4, nl = lane & 15;
#pragma unroll
    for (int f = 0; f < 4; f++)
#pragma unroll
        for (int g = 0; g < 4; g++)
#pragma unroll
            for (int reg = 0; reg < 4; reg++) {
                int row = m0 + wm * 64 + f * 16 + q * 4 + reg;
                int col = n0 + wn * 64 + g * 16 + nl;
                Cb[(size_t)row * ldC + col] = f2bf(acc[f][g][reg] * scale);
            }
}

// sum split-K bf16 partials + epilogue
__global__ __launch_bounds__(256) void k_reduce(const u16* __restrict__ part, size_t stride,
                                                int SK, int total, int N, float scale,
                                                const float* __restrict__ bias,
                                                float* __restrict__ outF, u16* __restrict__ outB) {
    int i = blockIdx.x * 256 + threadIdx.x;
    if (i >= total) return;
    float s = 0.f;
    for (int z = 0; z < SK; z++) s += bf2f(part[(size_t)z * stride + i]);
    float v = s * scale + (bias ? bias[i % N] : 0.0f);
    if (outF) outF[i] = v;
    else      outB[i] = f2bf(v);
}

// ---------------------------------------------------------------- rowwise LN
__device__ __forceinline__ float blockReduce(float v, float* red) {
#pragma unroll
    for (int off = 32; off > 0; off >>= 1) v += __shfl_down(v, off);
    __syncthreads();
    if ((threadIdx.x & 63) == 0) red[threadIdx.x >> 6] = v;
    __syncthreads();
    return red[0] + red[1] + red[2] + red[3];
}

__global__ __launch_bounds__(256) void k_ln_fwd(const float* __restrict__ X, int D,
    const float* __restrict__ g, const float* __restrict__ be,
    float* __restrict__ mu_out, float* __restrict__ r_out,
    u16* __restrict__ a_bf, float* __restrict__ a_f32) {
    __shared__ float red[4];
    int b = blockIdx.x, tid = threadIdx.x;
    const float* x = X + (size_t)b * D;
    int nd = D >> 8;
    float s = 0.f, s2 = 0.f;
    for (int r = 0; r < nd; r++) { float v = x[tid + (r << 8)]; s += v; s2 += v * v; }
    s = blockReduce(s, red);
    s2 = blockReduce(s2, red);
    float mu = s / D;
    float var = s2 / D - mu * mu;
    float rst = rsqrtf(var + 1e-6f);
    if (tid == 0) { mu_out[b] = mu; r_out[b] = rst; }
    for (int r = 0; r < nd; r++) {
        int i = tid + (r << 8);
        float xh = (x[i] - mu) * rst;
        float ln = xh * g[i] + be[i];
        float a = ln / (1.0f + expf(-ln));
        if (a_bf)  a_bf[(size_t)b * D + i] = f2bf(a);
        if (a_f32) a_f32[(size_t)b * D + i] = a;
    }
}

__global__ __launch_bounds__(256) void k_ln_bwd(const float* __restrict__ dup,
    const float* __restrict__ X, const float* __restrict__ mu_in, const float* __restrict__ r_in,
    const float* __restrict__ g, const float* __restrict__ be,
    u16* __restrict__ out_bf, int D) {
    __shared__ float red[4];
    int b = blockIdx.x, tid = threadIdx.x;
    const float* x = X + (size_t)b * D;
    float mu = mu_in[b], rst = r_in[b];
    int nd = D >> 8;
    float w_[4], xh_[4];
    float sw = 0.f, swx = 0.f;
    for (int r = 0; r < nd; r++) {
        int i = tid + (r << 8);
        float xh = (x[i] - mu) * rst;
        float ln = xh * g[i] + be[i];
        float sg = 1.0f / (1.0f + expf(-ln));
        float dsilu = sg * (1.0f + ln * (1.0f - sg));
        float d = dup ? dup[(size_t)b * D + i] : 1.0f;
        float w = g[i] * dsilu * d;
        w_[r] = w; xh_[r] = xh;
        sw += w; swx += w * xh;
    }
    sw = blockReduce(sw, red);
    swx = blockReduce(swx, red);
    float invD = 1.0f / D;
    for (int r = 0; r < nd; r++) {
        int i = tid + (r << 8);
        float dx = rst * (w_[r] - sw * invD - xh_[r] * swx * invD);
        out_bf[(size_t)b * D + i] = f2bf(dx);
    }
}

// ---------------------------------------------------------------- packed contraction
// y[b,a] = sum_v Gsym[a,v] x[v]. Shuffle-free: per-thread-owned outputs with
// serial accumulation over a v-range + one small LDS combine per segment.
__global__ __launch_bounds__(256) void k_contract_p(const u16* __restrict__ Gp,
                                                    const float* __restrict__ t,
                                                    float* __restrict__ y) {
    __shared__ u16 gp_s[NPACK];
    __shared__ float xs[480];
    __shared__ float red[1280];
    int b = blockIdx.x, tid = threadIdx.x;
    const uint4* gsrc = (const uint4*)(Gp + (size_t)b * NPACK);
    for (int j = tid; j < NPACK / 8; j += 256) ((uint4*)gp_s)[j] = gsrc[j];
    for (int j = tid; j < 480; j += 256) xs[j] = t[(size_t)b * 480 + j];
    __syncthreads();
    float* yr = y + (size_t)b * 480;

    // seg0: 128 outputs x 128 terms. thread = (u, half): 64 MACs, 2-way combine.
    {
        int u = tid & 127, half = tid >> 7;
        int v0 = half * 64;
        float s = 0.f;
#pragma unroll 8
        for (int i = 0; i < 64; i++) {
            int v = v0 + i;
            s += bf2f(gp_s[pk0(u, v)]) * xs[v];
        }
        red[tid] = s;
    }
    __syncthreads();
    if (tid < 128) yr[tid] = red[tid] + red[tid + 128];
    __syncthreads();

    // seg1: 64 outputs x 3 m x 64 terms. thread = (u, q): 16 v, 4-way combine.
    {
        int u = tid & 63, q = tid >> 6;
        int v0 = q * 16;
        float a0 = 0.f, a1 = 0.f, a2 = 0.f;
#pragma unroll 4
        for (int i = 0; i < 16; i++) {
            int v = v0 + i;
            float gv = bf2f(gp_s[pk1(u, v)]);
            a0 += gv * xs[128 + v * 3 + 0];
            a1 += gv * xs[128 + v * 3 + 1];
            a2 += gv * xs[128 + v * 3 + 2];
        }
        int base = (u * 4 + q) * 3;
        red[base + 0] = a0; red[base + 1] = a1; red[base + 2] = a2;
    }
    __syncthreads();
    if (tid < 192) {
        int u = tid / 3, m = tid - u * 3;
        float s = 0.f;
#pragma unroll
        for (int q = 0; q < 4; q++) s += red[(u * 4 + q) * 3 + m];
        yr[128 + u * 3 + m] = s;
    }
    __syncthreads();

    // seg2: 32 outputs x 5 m x 32 terms. thread = (u, o): 4 v, 8-way combine.
    {
        int u = tid & 31, o = tid >> 5;
        int v0 = o * 4;
        float a[5] = {0.f, 0.f, 0.f, 0.f, 0.f};
#pragma unroll
        for (int i = 0; i < 4; i++) {
            int v = v0 + i;
            float gv = bf2f(gp_s[pk2(u, v)]);
#pragma unroll
            for (int m = 0; m < 5; m++) a[m] += gv * xs[320 + v * 5 + m];
        }
        int base = (u * 8 + o) * 5;
#pragma unroll
        for (int m = 0; m < 5; m++) red[base + m] = a[m];
    }
    __syncthreads();
    if (tid < 160) {
        int u = tid / 5, m = tid - u * 5;
        float s = 0.f;
#pragma unroll
        for (int o = 0; o < 8; o++) s += red[(u * 8 + o) * 5 + m];
        yr[320 + u * 5 + m] = s;
    }
}

// ---------------------------------------------------------------- launch
extern "C" void kernel_launch(void* const* d_in, const int* in_sizes, int n_in,
                              void* d_out, int out_size, void* d_ws, size_t ws_size,
                              hipStream_t stream) {
    const float* t   = (const float*)d_in[0];
    const float* w0  = (const float*)d_in[1];
    const float* w1  = (const float*)d_in[2];
    const float* w2  = (const float*)d_in[3];
    const float* W1  = (const float*)d_in[4];
    const float* b1  = (const float*)d_in[5];
    const float* g1  = (const float*)d_in[6];
    const float* be1 = (const float*)d_in[7];
    const float* W2  = (const float*)d_in[8];
    const float* b2  = (const float*)d_in[9];
    const float* g2  = (const float*)d_in[10];
    const float* be2 = (const float*)d_in[11];

    float* xout = (float*)d_out;                    // 2048*256
    float* yout = xout + (size_t)2048 * 256;        // 2048*480

    char* ws = (char*)d_ws;
    size_t off = 0;
    auto alloc = [&](size_t bytes) -> void* {
        void* p = ws + off;
        off += (bytes + 255) & ~(size_t)255;
        return p;
    };
    u16*   PG    = (u16*)alloc((size_t)2048 * NPACK * 2);   // Ppack, later Gp (aliased)
    u16*   Wsym  = (u16*)alloc((size_t)NPACK * 1024 * 2);   // packed Wsym [i,h]
    u16*   Wt    = (u16*)alloc((size_t)1024 * NPACK * 2);   // packed Wsym^T [h,i]
    u16*   uvtab = (u16*)alloc((size_t)NPACK * 2);
    u16*   W1b   = (u16*)alloc((size_t)1024 * 1024 * 2);
    u16*   W1tb  = (u16*)alloc((size_t)1024 * 1024 * 2);
    u16*   W2b   = (u16*)alloc((size_t)1024 * 256 * 2);
    u16*   W2tb  = (u16*)alloc((size_t)256 * 1024 * 2);
    u16*   h_bf  = (u16*)alloc((size_t)2048 * 1024 * 2);
    float* h1pre = (float*)alloc((size_t)2048 * 1024 * 4);
    float* mu1   = (float*)alloc(2048 * 4);
    float* r1    = (float*)alloc(2048 * 4);
    u16*   a1_bf = (u16*)alloc((size_t)2048 * 1024 * 2);
    float* h2pre = (float*)alloc((size_t)2048 * 256 * 4);
    float* mu2   = (float*)alloc(2048 * 4);
    float* r2    = (float*)alloc(2048 * 4);
    u16*   dh2b  = (u16*)alloc((size_t)2048 * 256 * 2);
    float* d_a1  = (float*)alloc((size_t)2048 * 1024 * 4);
    u16*   dh1b  = (u16*)alloc((size_t)2048 * 1024 * 2);
    u16*   de_bf = (u16*)alloc((size_t)2048 * 1024 * 2);
    u16*   Cpart = (u16*)(ws + off);
    size_t cpartBytes = (ws_size > off) ? (ws_size - off) : 0;
    (void)in_sizes; (void)n_in; (void)out_size;

    const float sF = 1.0f / sqrtf(21504.0f);

    // generic GEMM helper (MLP GEMMs): 3-D grid, optional split-K (bf16 partials)
    auto gemm = [&](const u16* A, int ldA, const u16* B, int ldB, int M, int N, int K,
                    int SKwant, float scale, const float* bias,
                    float* Cf, u16* Cb, int ldC) {
        int SK = SKwant;
        size_t slice = (size_t)M * ldC * 2;
        if (SK > 1 && cpartBytes < 2 * slice) SK = 1;
        if (SK > 1 && (size_t)SK * slice > cpartBytes) SK = (int)(cpartBytes / slice);
        while (SK > 1 && !((K % SK) == 0 && ((K / SK) % 64) == 0)) SK--;
        dim3 grid(N / 128, M / 128, SK);
        if (SK > 1) {
            k_gemm2<<<grid, 256, 0, stream>>>(A, ldA, B, ldB, K / SK, 0.f, nullptr,
                                              nullptr, nullptr, ldC, Cpart, M, 0);
            int total = M * ldC;
            k_reduce<<<(total + 255) / 256, 256, 0, stream>>>(Cpart, (size_t)M * ldC, SK,
                                                              total, N, scale, bias, Cf, Cb);
        } else {
            k_gemm2<<<grid, 256, 0, stream>>>(A, ldA, B, ldB, K, scale, bias,
                                              Cf, Cb, ldC, nullptr, M, 0);
        }
    };

    // fused prep: uv table + W transposes + W converts (one launch)
    k_prep<<<2646, 256, 0, stream>>>(uvtab, W1, W2, W1b, W1tb, W2b, W2tb);
    // packed weights (needs uvtab)
    k_packw<<<dim3(NPACK / 32, 4), 256, 0, stream>>>(w0, w1, w2, uvtab, Wsym, Wt);

    // packed features
    k_features_pack<<<2048, 256, 0, stream>>>(t, uvtab, PG);

    // GEMM1: h = sF * Ppack @ Wt^T. 256-tile: 8z x (4nT x 8mT) = 256 blocks, kLen=1408.
    k_gemm256<<<dim3(256), 512, 0, stream>>>(PG, NPACK, Wt, NPACK, NPACK / 8, 0.f, nullptr,
                                             nullptr, 1024, Cpart, 2048, 1);
    {
        int total = 2048 * 1024;
        k_reduce<<<(total + 255) / 256, 256, 0, stream>>>(Cpart, (size_t)2048 * 1024, 8,
                                                          total, 1024, sF, nullptr,
                                                          nullptr, h_bf);
    }

    // MLP forward
    gemm(h_bf, 1024, W1tb, 1024, 2048, 1024, 1024, 4, 1.0f, b1, h1pre, nullptr, 1024);
    k_ln_fwd<<<2048, 256, 0, stream>>>(h1pre, 1024, g1, be1, mu1, r1, a1_bf, nullptr);
    gemm(a1_bf, 1024, W2tb, 1024, 2048, 256, 1024, 8, 1.0f, b2, h2pre, nullptr, 256);
    k_ln_fwd<<<2048, 256, 0, stream>>>(h2pre, 256, g2, be2, mu2, r2, nullptr, xout);

    // backward
    k_ln_bwd<<<2048, 256, 0, stream>>>(nullptr, h2pre, mu2, r2, g2, be2, dh2b, 256);
    gemm(dh2b, 256, W2b, 256, 2048, 1024, 256, 4, 1.0f, nullptr, d_a1, nullptr, 1024);
    k_ln_bwd<<<2048, 256, 0, stream>>>(d_a1, h1pre, mu1, r1, g1, be1, dh1b, 1024);
    gemm(dh1b, 1024, W1b, 1024, 2048, 1024, 1024, 4, sF, nullptr, nullptr, de_bf, 1024);

    // GEMM2: Gp = de @ Wsym^T. 128x256-tile, 3-buffer counted-vmcnt pipeline.
    u16* Gp = PG;   // Ppack dead after GEMM1
    k_gemm128n<<<dim3(704), 512, 0, stream>>>(de_bf, 1024, Wsym, 1024, 1024, 1.0f,
                                              Gp, NPACK);

    // y from packed symmetric Gp (shuffle-free contraction)
    k_contract_p<<<2048, 256, 0, stream>>>(Gp, t, yout);
}

// Round 10
// 424.904 us; speedup vs baseline: 1.0283x; 1.0283x over previous
//
#include <hip/hip_runtime.h>
#include <math.h>

typedef unsigned short u16;
typedef __bf16 bf16x8 __attribute__((ext_vector_type(8)));
typedef float f32x4 __attribute__((ext_vector_type(4)));

#define NPACK  11264   // padded packed-pair count (88*128)
#define NVALID 10864   // 8256 + 2080 + 528
#define BASE1  8256
#define BASE2  10336

__device__ __forceinline__ u16 f2bf(float f) {
    unsigned u = __builtin_bit_cast(unsigned, f);
    u += 0x7FFFu + ((u >> 16) & 1u);
    return (u16)(u >> 16);
}
__device__ __forceinline__ float bf2f(u16 h) {
    return __builtin_bit_cast(float, ((unsigned)h) << 16);
}

#define GLOAD_LDS16(g, l)                                                     \
    __builtin_amdgcn_global_load_lds(                                         \
        (const __attribute__((address_space(1))) void*)(g),                   \
        (__attribute__((address_space(3))) void*)(l), 16, 0, 0)

// packed triangular index (u<=v), per segment
__device__ __forceinline__ int pk0(int a, int b) {
    int u = min(a, b), v = max(a, b);
    return u * 128 - (u * (u - 1)) / 2 + (v - u);
}
__device__ __forceinline__ int pk1(int a, int b) {
    int u = min(a, b), v = max(a, b);
    return BASE1 + u * 64 - (u * (u - 1)) / 2 + (v - u);
}
__device__ __forceinline__ int pk2(int a, int b) {
    int u = min(a, b), v = max(a, b);
    return BASE2 + u * 32 - (u * (u - 1)) / 2 + (v - u);
}

// ---------------------------------------------------------------- fused prep
// bid <  86    : uv table
// 86..1109     : transpose W1 (32x32 tiles, grid 32x32)
// 1110..1365   : transpose W2 (grid 8x32)
// 1366..2389   : convert W1
// 2390..2645   : convert W2
__device__ __forceinline__ void prep_transpose(const float* __restrict__ in, int C,
                                               u16* __restrict__ out, int ldOut,
                                               int bx, int by, int tid) {
    __shared__ float tile[32][33];
    int tr0 = by * 32, tc0 = bx * 32;
    int lr = tid >> 5, lc = tid & 31;
#pragma unroll
    for (int i = 0; i < 4; i++) {
        int rr = lr + i * 8;
        tile[rr][lc] = in[(size_t)(tr0 + rr) * C + tc0 + lc];
    }
    __syncthreads();
#pragma unroll
    for (int i = 0; i < 4; i++) {
        int rr = lr + i * 8;
        out[(size_t)(tc0 + rr) * ldOut + tr0 + lc] = f2bf(tile[lc][rr]);
    }
}
__device__ __forceinline__ void prep_convert(const float* __restrict__ in,
                                             u16* __restrict__ out, int i, int n4) {
    if (i >= n4) return;
    float4 v = ((const float4*)in)[i];
    union { u16 a[4]; unsigned long long q; } o;
    o.a[0] = f2bf(v.x); o.a[1] = f2bf(v.y); o.a[2] = f2bf(v.z); o.a[3] = f2bf(v.w);
    ((unsigned long long*)out)[i] = o.q;
}

__global__ __launch_bounds__(256) void k_prep(u16* __restrict__ tab,
                                              const float* __restrict__ W1,
                                              const float* __restrict__ W2,
                                              u16* __restrict__ W1b,
                                              u16* __restrict__ W1tb,
                                              u16* __restrict__ W2b,
                                              u16* __restrict__ W2tb) {
    int bid = blockIdx.x, tid = threadIdx.x;
    if (bid < 86) {
        int j = bid * 256 + tid;
        if (j < 16384) {
            int u = j >> 7, v = j & 127;
            if (v >= u) tab[pk0(u, v)] = (u16)((u << 7) | v);
        } else if (j < 20480) {
            int k = j - 16384, u = k >> 6, v = k & 63;
            if (v >= u) tab[pk1(u, v)] = (u16)((1 << 14) | (u << 7) | v);
        } else if (j < 21504) {
            int k = j - 20480, u = k >> 5, v = k & 31;
            if (v >= u) tab[pk2(u, v)] = (u16)((2 << 14) | (u << 7) | v);
        } else if (j < 21504 + (NPACK - NVALID)) {
            tab[NVALID + (j - 21504)] = 0xFFFFu;
        }
    } else if (bid < 1110) {
        int k = bid - 86;                       // grid 32x32
        prep_transpose(W1, 1024, W1tb, 1024, k & 31, k >> 5, tid);
    } else if (bid < 1366) {
        int k = bid - 1110;                     // grid 8x32
        prep_transpose(W2, 256, W2tb, 1024, k & 7, k >> 3, tid);
    } else if (bid < 2390) {
        prep_convert(W1, W1b, (bid - 1366) * 256 + tid, 1024 * 1024 / 4);
    } else {
        prep_convert(W2, W2b, (bid - 2390) * 256 + tid, 1024 * 256 / 4);
    }
}

// ---------------------------------------------------------------- packed weights
__global__ __launch_bounds__(256) void k_packw(const float* __restrict__ w0,
                                               const float* __restrict__ w1,
                                               const float* __restrict__ w2,
                                               const u16* __restrict__ tab,
                                               u16* __restrict__ Wsym,
                                               u16* __restrict__ Wt) {
    __shared__ u16 tile[32][258];
    __shared__ u16 te[32];
    int i0 = blockIdx.x * 32, h0 = blockIdx.y * 256, tid = threadIdx.x;
    if (tid < 32) te[tid] = tab[i0 + tid];
    __syncthreads();
    const float s1 = 0.57735026918962576f, s2 = 0.44721359549995794f;
    for (int il = 0; il < 32; il++) {
        unsigned e = te[il];
        float val = 0.f;
        if ((e >> 14) != 3) {
            int seg = e >> 14, u = (e >> 7) & 127, v = e & 127;
            const float* wb; int S; float sc;
            if (seg == 0)      { wb = w0; S = 128; sc = 1.f; }
            else if (seg == 1) { wb = w1; S = 64;  sc = s1; }
            else               { wb = w2; S = 32;  sc = s2; }
            val = sc * (wb[(size_t)(u * S + v) * 1024 + h0 + tid] +
                        wb[(size_t)(v * S + u) * 1024 + h0 + tid]);
        }
        u16 bv = f2bf(val);
        Wsym[(size_t)(i0 + il) * 1024 + h0 + tid] = bv;
        tile[il][tid] = bv;
    }
    __syncthreads();
    union { u16 a[32]; uint4 q[4]; } pk;
#pragma unroll
    for (int il = 0; il < 32; il++) pk.a[il] = tile[il][tid];
    uint4* dst = (uint4*)(Wt + (size_t)(h0 + tid) * NPACK + i0);
#pragma unroll
    for (int q = 0; q < 4; q++) dst[q] = pk.q[q];
}

// ---------------------------------------------------------------- packed features
__global__ __launch_bounds__(256) void k_features_pack(const float* __restrict__ t,
                                                       const u16* __restrict__ tab,
                                                       u16* __restrict__ P) {
    __shared__ u16 tab_s[NPACK];
    __shared__ float tr[480];
    int b = blockIdx.x, tid = threadIdx.x;
    for (int j = tid; j < NPACK / 8; j += 256)
        ((uint4*)tab_s)[j] = ((const uint4*)tab)[j];
    for (int j = tid; j < 480; j += 256) tr[j] = t[(size_t)b * 480 + j];
    __syncthreads();
    u16* row = P + (size_t)b * NPACK;
    for (int i = tid; i < NPACK; i += 256) {
        unsigned e = tab_s[i];
        float p = 0.f;
        if ((e >> 14) != 3) {
            int seg = e >> 14, u = (e >> 7) & 127, v = e & 127;
            if (seg == 0) p = tr[u] * tr[v];
            else if (seg == 1) {
                const float* x1 = tr + 128;
                p = x1[u*3]*x1[v*3] + x1[u*3+1]*x1[v*3+1] + x1[u*3+2]*x1[v*3+2];
            } else {
                const float* x2 = tr + 320;
#pragma unroll
                for (int m = 0; m < 5; m++) p += x2[u*5+m] * x2[v*5+m];
            }
            if (u == v) p *= 0.5f;
        }
        row[i] = f2bf(p);
    }
}

// ---------------------------------------------------------------- GEMM 128-tile (MLP sizes)
__global__ __launch_bounds__(256) void k_gemm2(const u16* __restrict__ A, int ldA,
                                               const u16* __restrict__ B, int ldB,
                                               int kLen, float scale,
                                               const float* __restrict__ bias,
                                               float* __restrict__ Cf,
                                               u16* __restrict__ Cb, int ldC,
                                               u16* __restrict__ Cpart, int Mtot,
                                               int swz) {
    __shared__ u16 As[2][128 * 32];
    __shared__ u16 Bs[2][128 * 32];
    const int tid = threadIdx.x;
    const int wave = tid >> 6, lane = tid & 63;
    const int wm = wave >> 1, wn = wave & 1;
    int nT, mT, z;
    if (swz == 1) {
        int L = blockIdx.x;
        z = L & 7; int r = L >> 3;
        nT = r >> 4; mT = r & 15;
    } else if (swz == 2) {
        int L = blockIdx.x;
        int c = L & 7, r = L >> 3;
        nT = (r % 11) * 8 + c; mT = r / 11; z = 0;
    } else {
        nT = blockIdx.x; mT = blockIdx.y; z = blockIdx.z;
    }
    const int m0 = mT * 128, n0 = nT * 128;
    const size_t kOff = (size_t)z * kLen;

    const int chl = (((lane & 3) ^ ((lane >> 3) & 3))) * 8;
    const u16* aG = A + (size_t)(m0 + wave * 32 + (lane >> 2)) * ldA + kOff + chl;
    const u16* bG = B + (size_t)(n0 + wave * 32 + (lane >> 2)) * ldB + kOff + chl;
    const size_t aS = (size_t)16 * ldA;
    const size_t bS = (size_t)16 * ldB;
    u16* aL0 = &As[0][(wave * 32) * 32];
    u16* aL1 = &As[0][(wave * 32 + 16) * 32];
    u16* aH0 = &As[1][(wave * 32) * 32];
    u16* aH1 = &As[1][(wave * 32 + 16) * 32];
    u16* bL0 = &Bs[0][(wave * 32) * 32];
    u16* bL1 = &Bs[0][(wave * 32 + 16) * 32];
    u16* bH0 = &Bs[1][(wave * 32) * 32];
    u16* bH1 = &Bs[1][(wave * 32 + 16) * 32];

    f32x4 acc[4][4];
#pragma unroll
    for (int i = 0; i < 4; i++)
#pragma unroll
        for (int j = 0; j < 4; j++) acc[i][j] = (f32x4){0.f, 0.f, 0.f, 0.f};

    const int ml = lane & 15, kq8 = lane >> 4;
    const int kqs = (kq8 ^ ((ml >> 1) & 3)) * 8;
    const u16* aRd0 = &As[0][(wm * 64 + ml) * 32 + kqs];
    const u16* bRd0 = &Bs[0][(wn * 64 + ml) * 32 + kqs];
    const u16* aRd1 = &As[1][(wm * 64 + ml) * 32 + kqs];
    const u16* bRd1 = &Bs[1][(wn * 64 + ml) * 32 + kqs];

    for (int k = 0; k < kLen; k += 64) {
        GLOAD_LDS16(aG, aL0);
        GLOAD_LDS16(aG + aS, aL1);
        GLOAD_LDS16(aG + 32, aH0);
        GLOAD_LDS16(aG + aS + 32, aH1);
        GLOAD_LDS16(bG, bL0);
        GLOAD_LDS16(bG + bS, bL1);
        GLOAD_LDS16(bG + 32, bH0);
        GLOAD_LDS16(bG + bS + 32, bH1);
        aG += 64; bG += 64;
        __syncthreads();
        {
            bf16x8 af[4], bfv[4];
#pragma unroll
            for (int i = 0; i < 4; i++) af[i]  = *(const bf16x8*)(aRd0 + i * 16 * 32);
#pragma unroll
            for (int j = 0; j < 4; j++) bfv[j] = *(const bf16x8*)(bRd0 + j * 16 * 32);
#pragma unroll
            for (int i = 0; i < 4; i++)
#pragma unroll
                for (int j = 0; j < 4; j++)
                    acc[i][j] = __builtin_amdgcn_mfma_f32_16x16x32_bf16(af[i], bfv[j], acc[i][j], 0, 0, 0);
        }
        {
            bf16x8 af[4], bfv[4];
#pragma unroll
            for (int i = 0; i < 4; i++) af[i]  = *(const bf16x8*)(aRd1 + i * 16 * 32);
#pragma unroll
            for (int j = 0; j < 4; j++) bfv[j] = *(const bf16x8*)(bRd1 + j * 16 * 32);
#pragma unroll
            for (int i = 0; i < 4; i++)
#pragma unroll
                for (int j = 0; j < 4; j++)
                    acc[i][j] = __builtin_amdgcn_mfma_f32_16x16x32_bf16(af[i], bfv[j], acc[i][j], 0, 0, 0);
        }
        __syncthreads();
    }

    const int q = lane >> 4, nl = lane & 15;
    if (Cpart) {
        u16* outP = Cpart + (size_t)z * Mtot * ldC;
#pragma unroll
        for (int i = 0; i < 4; i++)
#pragma unroll
            for (int j = 0; j < 4; j++)
#pragma unroll
                for (int reg = 0; reg < 4; reg++) {
                    int row = m0 + wm * 64 + i * 16 + q * 4 + reg;
                    int col = n0 + wn * 64 + j * 16 + nl;
                    outP[(size_t)row * ldC + col] = f2bf(acc[i][j][reg]);
                }
    } else {
#pragma unroll
        for (int i = 0; i < 4; i++)
#pragma unroll
            for (int j = 0; j < 4; j++)
#pragma unroll
                for (int reg = 0; reg < 4; reg++) {
                    int row = m0 + wm * 64 + i * 16 + q * 4 + reg;
                    int col = n0 + wn * 64 + j * 16 + nl;
                    float v = acc[i][j][reg] * scale + (bias ? bias[col] : 0.0f);
                    if (Cf) Cf[(size_t)row * ldC + col] = v;
                    else    Cb[(size_t)row * ldC + col] = f2bf(v);
                }
    }
}

// ---------------------------------------------------------------- GEMM 256-tile (GEMM1), R3 schedule
#define VMCNT0 asm volatile("s_waitcnt vmcnt(0)" ::: "memory")
#define VMCNT6 asm volatile("s_waitcnt vmcnt(6)" ::: "memory")
#define BARX() __builtin_amdgcn_s_barrier()

#define STG_A(p, kh, rh, kb) GLOAD_LDS16(aB + (size_t)(rh) * aH + (kb) + (kh) * 32, \
                                         &As[p][kh][((rh) * 128 + wave * 16) * 32])
#define STG_B(p, kh, rh, kb) GLOAD_LDS16(bB + (size_t)(rh) * bH + (kb) + (kh) * 32, \
                                         &Bs[p][kh][((rh) * 128 + wave * 16) * 32])
#define MMQ(fb, gb, bv) do { _Pragma("unroll") \
    for (int ff = 0; ff < 4; ff++) { _Pragma("unroll") \
        for (int gg = 0; gg < 2; gg++) { \
            acc[(fb)+ff][(gb)+gg] = __builtin_amdgcn_mfma_f32_16x16x32_bf16(a[2*ff],   bv[2*gg],   acc[(fb)+ff][(gb)+gg], 0, 0, 0); \
            acc[(fb)+ff][(gb)+gg] = __builtin_amdgcn_mfma_f32_16x16x32_bf16(a[2*ff+1], bv[2*gg+1], acc[(fb)+ff][(gb)+gg], 0, 0, 0); } } } while (0)

__global__ __launch_bounds__(512, 2) void k_gemm256(const u16* __restrict__ A, int ldA,
                                                    const u16* __restrict__ B, int ldB,
                                                    int kLen, float scale,
                                                    const float* __restrict__ bias,
                                                    u16* __restrict__ Cb, int ldC,
                                                    u16* __restrict__ Cpart, int Mtot,
                                                    int swz) {
    __shared__ __align__(16) u16 As[2][2][256 * 32];   // [buf][kh][row*32+k]  64 KB
    __shared__ __align__(16) u16 Bs[2][2][256 * 32];   // 64 KB
    const int tid = threadIdx.x;
    const int lane = tid & 63, wave = tid >> 6;
    const int wm = wave >> 2, wn = wave & 3;
    int mT, nT, z;
    if (swz == 1) {
        // GEMM1: 256 blocks. XCD = z = L&7. Within XCD: nT fastest.
        z = blockIdx.x & 7; int r = blockIdx.x >> 3; nT = r & 3; mT = r >> 2;
    } else {
        int x = blockIdx.x & 7, j = blockIdx.x >> 3;
        int nti = j >> 3; mT = j & 7;
        if (nti < 5)      nT = nti * 8 + x;
        else if (x < 4)   nT = 40 + x;
        else            { nT = 40 + (x - 4); mT = (j & 7) + 4; }
        z = 0;
    }
    const int m0 = mT * 256, n0 = nT * 256;
    const size_t kOff = (size_t)z * kLen;
    const int nTi = kLen >> 6;          // K-64 tiles, >= 2

    const int chl = ((tid & 3) ^ ((tid >> 3) & 3)) * 8;
    const u16* aB = A + (size_t)(m0 + (tid >> 2)) * ldA + kOff + chl;
    const u16* bB = B + (size_t)(n0 + (tid >> 2)) * ldB + kOff + chl;
    const size_t aH = (size_t)128 * ldA;
    const size_t bH = (size_t)128 * ldB;

    const int ml = lane & 15, kq8 = lane >> 4;
    const int kqs = (kq8 ^ ((ml >> 1) & 3)) * 8;
    const int aro = (wm * 128 + ml) * 32 + kqs;
    const int bro = (wn * 64 + ml) * 32 + kqs;

    f32x4 acc[8][4];
#pragma unroll
    for (int f = 0; f < 8; f++)
#pragma unroll
        for (int g = 0; g < 4; g++) acc[f][g] = (f32x4){0.f, 0.f, 0.f, 0.f};
    bf16x8 a[8], b[4], b2[4];

    STG_A(0, 0, 0, 0); STG_A(0, 0, 1, 0); STG_A(0, 1, 0, 0); STG_A(0, 1, 1, 0);
    STG_B(0, 0, 0, 0); STG_B(0, 0, 1, 0); STG_B(0, 1, 0, 0); STG_B(0, 1, 1, 0);
    VMCNT0;
    BARX();

    for (int t = 0; t < nTi; t++) {
        const int p = t & 1, p1 = p ^ 1;
        const int kb1 = (t + 1) << 6;
        const bool s1 = (t + 1) < nTi;
        // phase 0
#pragma unroll
        for (int f = 0; f < 4; f++) {
            a[2*f]   = *(const bf16x8*)&As[p][0][aro + f * 512];
            a[2*f+1] = *(const bf16x8*)&As[p][1][aro + f * 512];
        }
#pragma unroll
        for (int g = 0; g < 2; g++) {
            b[2*g]   = *(const bf16x8*)&Bs[p][0][bro + g * 512];
            b[2*g+1] = *(const bf16x8*)&Bs[p][1][bro + g * 512];
        }
        if (s1) { STG_A(p1, 0, 0, kb1); STG_A(p1, 0, 1, kb1); }
        BARX();
        __builtin_amdgcn_s_setprio(1);
        MMQ(0, 0, b);
        __builtin_amdgcn_s_setprio(0);
        BARX();
        // phase 1
#pragma unroll
        for (int g = 0; g < 2; g++) {
            b2[2*g]   = *(const bf16x8*)&Bs[p][0][bro + (g + 2) * 512];
            b2[2*g+1] = *(const bf16x8*)&Bs[p][1][bro + (g + 2) * 512];
        }
        if (s1) { STG_A(p1, 1, 0, kb1); STG_A(p1, 1, 1, kb1); }
        BARX();
        __builtin_amdgcn_s_setprio(1);
        MMQ(0, 2, b2);
        __builtin_amdgcn_s_setprio(0);
        BARX();
        // phase 2
#pragma unroll
        for (int f = 0; f < 4; f++) {
            a[2*f]   = *(const bf16x8*)&As[p][0][aro + (f + 4) * 512];
            a[2*f+1] = *(const bf16x8*)&As[p][1][aro + (f + 4) * 512];
        }
        if (s1) { STG_B(p1, 0, 0, kb1); STG_B(p1, 0, 1, kb1); }
        BARX();
        __builtin_amdgcn_s_setprio(1);
        MMQ(4, 0, b);
        __builtin_amdgcn_s_setprio(0);
        BARX();
        // phase 3
        if (s1) { STG_B(p1, 1, 0, kb1); STG_B(p1, 1, 1, kb1); }
        __builtin_amdgcn_s_setprio(1);
        MMQ(4, 2, b2);
        __builtin_amdgcn_s_setprio(0);
        if (s1) VMCNT0;
        BARX();
    }

    const int q = lane >> 4, nl = lane & 15;
    if (Cpart) {
        u16* outP = Cpart + (size_t)z * Mtot * ldC;
#pragma unroll
        for (int f = 0; f < 8; f++)
#pragma unroll
            for (int g = 0; g < 4; g++)
#pragma unroll
                for (int reg = 0; reg < 4; reg++) {
                    int row = m0 + wm * 128 + f * 16 + q * 4 + reg;
                    int col = n0 + wn * 64 + g * 16 + nl;
                    outP[(size_t)row * ldC + col] = f2bf(acc[f][g][reg]);
                }
    } else {
#pragma unroll
        for (int f = 0; f < 8; f++)
#pragma unroll
            for (int g = 0; g < 4; g++)
#pragma unroll
                for (int reg = 0; reg < 4; reg++) {
                    int row = m0 + wm * 128 + f * 16 + q * 4 + reg;
                    int col = n0 + wn * 64 + g * 16 + nl;
                    float v = acc[f][g][reg] * scale + (bias ? bias[col] : 0.0f);
                    Cb[(size_t)row * ldC + col] = f2bf(v);
                }
    }
}

// ---------------------------------------------------------------- GEMM 128x256-tile (GEMM2)
// 3-buffer 2-deep pipeline, counted vmcnt(6) boundary (R9 structure).
#define MMQ22(fb, gb, bv) do { _Pragma("unroll") \
    for (int ff = 0; ff < 2; ff++) { _Pragma("unroll") \
        for (int gg = 0; gg < 2; gg++) { \
            acc[(fb)+ff][(gb)+gg] = __builtin_amdgcn_mfma_f32_16x16x32_bf16(a[2*ff],   bv[2*gg],   acc[(fb)+ff][(gb)+gg], 0, 0, 0); \
            acc[(fb)+ff][(gb)+gg] = __builtin_amdgcn_mfma_f32_16x16x32_bf16(a[2*ff+1], bv[2*gg+1], acc[(fb)+ff][(gb)+gg], 0, 0, 0); } } } while (0)

__global__ __launch_bounds__(512, 2) void k_gemm128n(const u16* __restrict__ A, int ldA,
                                                     const u16* __restrict__ B, int ldB,
                                                     int kLen, float scale,
                                                     u16* __restrict__ Cb, int ldC) {
    __shared__ __align__(16) u16 As[3][2][128 * 32];   // 48 KB
    __shared__ __align__(16) u16 Bs[3][2][256 * 32];   // 96 KB
    const int tid = threadIdx.x;
    const int lane = tid & 63, wave = tid >> 6;
    const int wm = wave >> 2, wn = wave & 3;           // wm 0..1, wn 0..3
    int x = blockIdx.x & 7, j = blockIdx.x >> 3;
    int nti = j >> 4, mT = j & 15, nT;
    if (nti < 5) nT = nti * 8 + x;
    else { nT = 40 + (x & 3); mT = (j & 7) + 8 * (x >> 2); }
    const int m0 = mT * 128, n0 = nT * 256;
    const int nTi = kLen >> 6;

    const int chl = ((tid & 3) ^ ((tid >> 3) & 3)) * 8;
    const u16* aB = A + (size_t)(m0 + (tid >> 2)) * ldA + chl;   // rows 0..127
    const u16* bB = B + (size_t)(n0 + (tid >> 2)) * ldB + chl;
    const size_t bH = (size_t)128 * ldB;

    const int ml = lane & 15, kq8 = lane >> 4;
    const int kqs = (kq8 ^ ((ml >> 1) & 3)) * 8;
    const int aro = (wm * 64 + ml) * 32 + kqs;
    const int bro = (wn * 64 + ml) * 32 + kqs;

    f32x4 acc[4][4];
#pragma unroll
    for (int f = 0; f < 4; f++)
#pragma unroll
        for (int g = 0; g < 4; g++) acc[f][g] = (f32x4){0.f, 0.f, 0.f, 0.f};
    bf16x8 a[4], b[4], b2[4];

#define SG_A(p, kh, kb) GLOAD_LDS16(aB + (kb) + (kh) * 32, &As[p][kh][(wave * 16) * 32])
#define SG_B(p, kh, rh, kb) GLOAD_LDS16(bB + (size_t)(rh) * bH + (kb) + (kh) * 32, \
                                        &Bs[p][kh][((rh) * 128 + wave * 16) * 32])

    // prologue: stage T0 -> buf0 (6) and T1 -> buf1 (6); retire T0; barrier.
    SG_A(0, 0, 0); SG_A(0, 1, 0);
    SG_B(0, 0, 0, 0); SG_B(0, 0, 1, 0); SG_B(0, 1, 0, 0); SG_B(0, 1, 1, 0);
    if (nTi > 1) {
        SG_A(1, 0, 64); SG_A(1, 1, 64);
        SG_B(1, 0, 0, 64); SG_B(1, 0, 1, 64); SG_B(1, 1, 0, 64); SG_B(1, 1, 1, 64);
        VMCNT6;
    } else {
        VMCNT0;
    }
    BARX();

    int p = 0;
    for (int t = 0; t < nTi; t++) {
        const int p2 = (p >= 1) ? p - 1 : 2;           // (t+2) % 3
        const int kb2 = (t + 2) << 6;
        const bool s2 = (t + 2) < nTi;
        const bool s1 = (t + 1) < nTi;
        // phase 0: a f0..1, b g0..1; stage t+2 A kh0+kh1
#pragma unroll
        for (int f = 0; f < 2; f++) {
            a[2*f]   = *(const bf16x8*)&As[p][0][aro + f * 512];
            a[2*f+1] = *(const bf16x8*)&As[p][1][aro + f * 512];
        }
#pragma unroll
        for (int g = 0; g < 2; g++) {
            b[2*g]   = *(const bf16x8*)&Bs[p][0][bro + g * 512];
            b[2*g+1] = *(const bf16x8*)&Bs[p][1][bro + g * 512];
        }
        if (s2) { SG_A(p2, 0, kb2); SG_A(p2, 1, kb2); }
        BARX();
        __builtin_amdgcn_s_setprio(1);
        MMQ22(0, 0, b);
        __builtin_amdgcn_s_setprio(0);
        BARX();
        // phase 1: b2 g2..3; stage t+2 B kh0
#pragma unroll
        for (int g = 0; g < 2; g++) {
            b2[2*g]   = *(const bf16x8*)&Bs[p][0][bro + (g + 2) * 512];
            b2[2*g+1] = *(const bf16x8*)&Bs[p][1][bro + (g + 2) * 512];
        }
        if (s2) { SG_B(p2, 0, 0, kb2); SG_B(p2, 0, 1, kb2); }
        BARX();
        __builtin_amdgcn_s_setprio(1);
        MMQ22(0, 2, b2);
        __builtin_amdgcn_s_setprio(0);
        BARX();
        // phase 2: a f2..3; stage t+2 B kh1
#pragma unroll
        for (int f = 0; f < 2; f++) {
            a[2*f]   = *(const bf16x8*)&As[p][0][aro + (f + 2) * 512];
            a[2*f+1] = *(const bf16x8*)&As[p][1][aro + (f + 2) * 512];
        }
        if (s2) { SG_B(p2, 1, 0, kb2); SG_B(p2, 1, 1, kb2); }
        BARX();
        __builtin_amdgcn_s_setprio(1);
        MMQ22(2, 0, b);
        __builtin_amdgcn_s_setprio(0);
        BARX();
        // phase 3: no reads/stages; counted boundary wait
        __builtin_amdgcn_s_setprio(1);
        MMQ22(2, 2, b2);
        __builtin_amdgcn_s_setprio(0);
        if (s2)      { VMCNT6; }   // retire t+1's 6 (old); t+2's 6 stay in flight
        else if (s1) { VMCNT0; }   // tail: only t+1's (old) loads outstanding
        BARX();
        p = (p == 2) ? 0 : p + 1;
    }

    const int q = lane >> 4, nl = lane & 15;
#pragma unroll
    for (int f = 0; f < 4; f++)
#pragma unroll
        for (int g = 0; g < 4; g++)
#pragma unroll
            for (int reg = 0; reg < 4; reg++) {
                int row = m0 + wm * 64 + f * 16 + q * 4 + reg;
                int col = n0 + wn * 64 + g * 16 + nl;
                Cb[(size_t)row * ldC + col] = f2bf(acc[f][g][reg] * scale);
            }
}

// sum split-K bf16 partials + epilogue
__global__ __launch_bounds__(256) void k_reduce(const u16* __restrict__ part, size_t stride,
                                                int SK, int total, int N, float scale,
                                                const float* __restrict__ bias,
                                                float* __restrict__ outF, u16* __restrict__ outB) {
    int i = blockIdx.x * 256 + threadIdx.x;
    if (i >= total) return;
    float s = 0.f;
    for (int z = 0; z < SK; z++) s += bf2f(part[(size_t)z * stride + i]);
    float v = s * scale + (bias ? bias[i % N] : 0.0f);
    if (outF) outF[i] = v;
    else      outB[i] = f2bf(v);
}

// ---------------------------------------------------------------- rowwise LN
__device__ __forceinline__ float blockReduce(float v, float* red) {
#pragma unroll
    for (int off = 32; off > 0; off >>= 1) v += __shfl_down(v, off);
    __syncthreads();
    if ((threadIdx.x & 63) == 0) red[threadIdx.x >> 6] = v;
    __syncthreads();
    return red[0] + red[1] + red[2] + red[3];
}

// Fused: split-K reduce + bias -> pre (stored f32 for bwd) -> LN + SiLU.
// One block per row; D in {256, 1024}; SK partials are bf16.
__global__ __launch_bounds__(256) void k_red_ln_fwd(const u16* __restrict__ part,
    size_t stride, int SK, int D,
    const float* __restrict__ bias,
    const float* __restrict__ g, const float* __restrict__ be,
    float* __restrict__ mu_out, float* __restrict__ r_out,
    float* __restrict__ pre_out,
    u16* __restrict__ a_bf, float* __restrict__ a_f32) {
    __shared__ float red[4];
    int b = blockIdx.x, tid = threadIdx.x;
    int nd = D >> 8;
    float v_[4];
    float s = 0.f, s2 = 0.f;
    for (int r = 0; r < nd; r++) {
        int i = tid + (r << 8);
        size_t idx = (size_t)b * D + i;
        float v = 0.f;
        for (int z = 0; z < SK; z++) v += bf2f(part[(size_t)z * stride + idx]);
        v += bias[i];
        v_[r] = v;
        pre_out[idx] = v;
        s += v; s2 += v * v;
    }
    s = blockReduce(s, red);
    s2 = blockReduce(s2, red);
    float mu = s / D;
    float var = s2 / D - mu * mu;
    float rst = rsqrtf(var + 1e-6f);
    if (tid == 0) { mu_out[b] = mu; r_out[b] = rst; }
    for (int r = 0; r < nd; r++) {
        int i = tid + (r << 8);
        float xh = (v_[r] - mu) * rst;
        float ln = xh * g[i] + be[i];
        float a = ln / (1.0f + expf(-ln));
        if (a_bf)  a_bf[(size_t)b * D + i] = f2bf(a);
        if (a_f32) a_f32[(size_t)b * D + i] = a;
    }
}

__global__ __launch_bounds__(256) void k_ln_bwd(const float* __restrict__ dup,
    const float* __restrict__ X, const float* __restrict__ mu_in, const float* __restrict__ r_in,
    const float* __restrict__ g, const float* __restrict__ be,
    u16* __restrict__ out_bf, int D) {
    __shared__ float red[4];
    int b = blockIdx.x, tid = threadIdx.x;
    const float* x = X + (size_t)b * D;
    float mu = mu_in[b], rst = r_in[b];
    int nd = D >> 8;
    float w_[4], xh_[4];
    float sw = 0.f, swx = 0.f;
    for (int r = 0; r < nd; r++) {
        int i = tid + (r << 8);
        float xh = (x[i] - mu) * rst;
        float ln = xh * g[i] + be[i];
        float sg = 1.0f / (1.0f + expf(-ln));
        float dsilu = sg * (1.0f + ln * (1.0f - sg));
        float d = dup ? dup[(size_t)b * D + i] : 1.0f;
        float w = g[i] * dsilu * d;
        w_[r] = w; xh_[r] = xh;
        sw += w; swx += w * xh;
    }
    sw = blockReduce(sw, red);
    swx = blockReduce(swx, red);
    float invD = 1.0f / D;
    for (int r = 0; r < nd; r++) {
        int i = tid + (r << 8);
        float dx = rst * (w_[r] - sw * invD - xh_[r] * swx * invD);
        out_bf[(size_t)b * D + i] = f2bf(dx);
    }
}

// Fused: split-K reduce (upstream grad, no bias) + LN backward.
__global__ __launch_bounds__(256) void k_red_ln_bwd(const u16* __restrict__ part,
    size_t stride, int SK,
    const float* __restrict__ X, const float* __restrict__ mu_in, const float* __restrict__ r_in,
    const float* __restrict__ g, const float* __restrict__ be,
    u16* __restrict__ out_bf, int D) {
    __shared__ float red[4];
    int b = blockIdx.x, tid = threadIdx.x;
    const float* x = X + (size_t)b * D;
    float mu = mu_in[b], rst = r_in[b];
    int nd = D >> 8;
    float w_[4], xh_[4];
    float sw = 0.f, swx = 0.f;
    for (int r = 0; r < nd; r++) {
        int i = tid + (r << 8);
        size_t idx = (size_t)b * D + i;
        float d = 0.f;
        for (int z = 0; z < SK; z++) d += bf2f(part[(size_t)z * stride + idx]);
        float xh = (x[i] - mu) * rst;
        float ln = xh * g[i] + be[i];
        float sg = 1.0f / (1.0f + expf(-ln));
        float dsilu = sg * (1.0f + ln * (1.0f - sg));
        float w = g[i] * dsilu * d;
        w_[r] = w; xh_[r] = xh;
        sw += w; swx += w * xh;
    }
    sw = blockReduce(sw, red);
    swx = blockReduce(swx, red);
    float invD = 1.0f / D;
    for (int r = 0; r < nd; r++) {
        int i = tid + (r << 8);
        float dx = rst * (w_[r] - sw * invD - xh_[r] * swx * invD);
        out_bf[(size_t)b * D + i] = f2bf(dx);
    }
}

// ---------------------------------------------------------------- packed contraction
// y[b,a] = sum_v Gsym[a,v] x[v]. Shuffle-free: per-thread-owned outputs with
// serial accumulation over a v-range + one small LDS combine per segment.
__global__ __launch_bounds__(256) void k_contract_p(const u16* __restrict__ Gp,
                                                    const float* __restrict__ t,
                                                    float* __restrict__ y) {
    __shared__ u16 gp_s[NPACK];
    __shared__ float xs[480];
    __shared__ float red[1280];
    int b = blockIdx.x, tid = threadIdx.x;
    const uint4* gsrc = (const uint4*)(Gp + (size_t)b * NPACK);
    for (int j = tid; j < NPACK / 8; j += 256) ((uint4*)gp_s)[j] = gsrc[j];
    for (int j = tid; j < 480; j += 256) xs[j] = t[(size_t)b * 480 + j];
    __syncthreads();
    float* yr = y + (size_t)b * 480;

    // seg0: 128 outputs x 128 terms. thread = (u, half): 64 MACs, 2-way combine.
    {
        int u = tid & 127, half = tid >> 7;
        int v0 = half * 64;
        float s = 0.f;
#pragma unroll 8
        for (int i = 0; i < 64; i++) {
            int v = v0 + i;
            s += bf2f(gp_s[pk0(u, v)]) * xs[v];
        }
        red[tid] = s;
    }
    __syncthreads();
    if (tid < 128) yr[tid] = red[tid] + red[tid + 128];
    __syncthreads();

    // seg1: 64 outputs x 3 m x 64 terms. thread = (u, q): 16 v, 4-way combine.
    {
        int u = tid & 63, q = tid >> 6;
        int v0 = q * 16;
        float a0 = 0.f, a1 = 0.f, a2 = 0.f;
#pragma unroll 4
        for (int i = 0; i < 16; i++) {
            int v = v0 + i;
            float gv = bf2f(gp_s[pk1(u, v)]);
            a0 += gv * xs[128 + v * 3 + 0];
            a1 += gv * xs[128 + v * 3 + 1];
            a2 += gv * xs[128 + v * 3 + 2];
        }
        int base = (u * 4 + q) * 3;
        red[base + 0] = a0; red[base + 1] = a1; red[base + 2] = a2;
    }
    __syncthreads();
    if (tid < 192) {
        int u = tid / 3, m = tid - u * 3;
        float s = 0.f;
#pragma unroll
        for (int q = 0; q < 4; q++) s += red[(u * 4 + q) * 3 + m];
        yr[128 + u * 3 + m] = s;
    }
    __syncthreads();

    // seg2: 32 outputs x 5 m x 32 terms. thread = (u, o): 4 v, 8-way combine.
    {
        int u = tid & 31, o = tid >> 5;
        int v0 = o * 4;
        float a[5] = {0.f, 0.f, 0.f, 0.f, 0.f};
#pragma unroll
        for (int i = 0; i < 4; i++) {
            int v = v0 + i;
            float gv = bf2f(gp_s[pk2(u, v)]);
#pragma unroll
            for (int m = 0; m < 5; m++) a[m] += gv * xs[320 + v * 5 + m];
        }
        int base = (u * 8 + o) * 5;
#pragma unroll
        for (int m = 0; m < 5; m++) red[base + m] = a[m];
    }
    __syncthreads();
    if (tid < 160) {
        int u = tid / 5, m = tid - u * 5;
        float s = 0.f;
#pragma unroll
        for (int o = 0; o < 8; o++) s += red[(u * 8 + o) * 5 + m];
        yr[320 + u * 5 + m] = s;
    }
}

// ---------------------------------------------------------------- launch
extern "C" void kernel_launch(void* const* d_in, const int* in_sizes, int n_in,
                              void* d_out, int out_size, void* d_ws, size_t ws_size,
                              hipStream_t stream) {
    const float* t   = (const float*)d_in[0];
    const float* w0  = (const float*)d_in[1];
    const float* w1  = (const float*)d_in[2];
    const float* w2  = (const float*)d_in[3];
    const float* W1  = (const float*)d_in[4];
    const float* b1  = (const float*)d_in[5];
    const float* g1  = (const float*)d_in[6];
    const float* be1 = (const float*)d_in[7];
    const float* W2  = (const float*)d_in[8];
    const float* b2  = (const float*)d_in[9];
    const float* g2  = (const float*)d_in[10];
    const float* be2 = (const float*)d_in[11];

    float* xout = (float*)d_out;                    // 2048*256
    float* yout = xout + (size_t)2048 * 256;        // 2048*480

    char* ws = (char*)d_ws;
    size_t off = 0;
    auto alloc = [&](size_t bytes) -> void* {
        void* p = ws + off;
        off += (bytes + 255) & ~(size_t)255;
        return p;
    };
    u16*   PG    = (u16*)alloc((size_t)2048 * NPACK * 2);   // Ppack, later Gp (aliased)
    u16*   Wsym  = (u16*)alloc((size_t)NPACK * 1024 * 2);   // packed Wsym [i,h]
    u16*   Wt    = (u16*)alloc((size_t)1024 * NPACK * 2);   // packed Wsym^T [h,i]
    u16*   uvtab = (u16*)alloc((size_t)NPACK * 2);
    u16*   W1b   = (u16*)alloc((size_t)1024 * 1024 * 2);
    u16*   W1tb  = (u16*)alloc((size_t)1024 * 1024 * 2);
    u16*   W2b   = (u16*)alloc((size_t)1024 * 256 * 2);
    u16*   W2tb  = (u16*)alloc((size_t)256 * 1024 * 2);
    u16*   h_bf  = (u16*)alloc((size_t)2048 * 1024 * 2);
    float* h1pre = (float*)alloc((size_t)2048 * 1024 * 4);
    float* mu1   = (float*)alloc(2048 * 4);
    float* r1    = (float*)alloc(2048 * 4);
    u16*   a1_bf = (u16*)alloc((size_t)2048 * 1024 * 2);
    float* h2pre = (float*)alloc((size_t)2048 * 256 * 4);
    float* mu2   = (float*)alloc(2048 * 4);
    float* r2    = (float*)alloc(2048 * 4);
    u16*   dh2b  = (u16*)alloc((size_t)2048 * 256 * 2);
    u16*   dh1b  = (u16*)alloc((size_t)2048 * 1024 * 2);
    u16*   de_bf = (u16*)alloc((size_t)2048 * 1024 * 2);
    u16*   Cpart = (u16*)(ws + off);
    size_t cpartBytes = (ws_size > off) ? (ws_size - off) : 0;
    (void)in_sizes; (void)n_in; (void)out_size;

    const float sF = 1.0f / sqrtf(21504.0f);

    // generic GEMM helper: 3-D grid, optional split-K (bf16 partials)
    auto gemm = [&](const u16* A, int ldA, const u16* B, int ldB, int M, int N, int K,
                    int SKwant, float scale, const float* bias,
                    float* Cf, u16* Cb, int ldC) {
        int SK = SKwant;
        size_t slice = (size_t)M * ldC * 2;
        if (SK > 1 && cpartBytes < 2 * slice) SK = 1;
        if (SK > 1 && (size_t)SK * slice > cpartBytes) SK = (int)(cpartBytes / slice);
        while (SK > 1 && !((K % SK) == 0 && ((K / SK) % 64) == 0)) SK--;
        dim3 grid(N / 128, M / 128, SK);
        if (SK > 1) {
            k_gemm2<<<grid, 256, 0, stream>>>(A, ldA, B, ldB, K / SK, 0.f, nullptr,
                                              nullptr, nullptr, ldC, Cpart, M, 0);
            int total = M * ldC;
            k_reduce<<<(total + 255) / 256, 256, 0, stream>>>(Cpart, (size_t)M * ldC, SK,
                                                              total, N, scale, bias, Cf, Cb);
        } else {
            k_gemm2<<<grid, 256, 0, stream>>>(A, ldA, B, ldB, K, scale, bias,
                                              Cf, Cb, ldC, nullptr, M, 0);
        }
    };

    // fused prep: uv table + W transposes + W converts (one launch)
    k_prep<<<2646, 256, 0, stream>>>(uvtab, W1, W2, W1b, W1tb, W2b, W2tb);
    // packed weights (needs uvtab)
    k_packw<<<dim3(NPACK / 32, 4), 256, 0, stream>>>(w0, w1, w2, uvtab, Wsym, Wt);

    // packed features
    k_features_pack<<<2048, 256, 0, stream>>>(t, uvtab, PG);

    // GEMM1: h = sF * Ppack @ Wt^T. 256-tile: 8z x (4nT x 8mT) = 256 blocks, kLen=1408.
    k_gemm256<<<dim3(256), 512, 0, stream>>>(PG, NPACK, Wt, NPACK, NPACK / 8, 0.f, nullptr,
                                             nullptr, 1024, Cpart, 2048, 1);
    {
        int total = 2048 * 1024;
        k_reduce<<<(total + 255) / 256, 256, 0, stream>>>(Cpart, (size_t)2048 * 1024, 8,
                                                          total, 1024, sF, nullptr,
                                                          nullptr, h_bf);
    }

    // MLP forward, fused reduce+LN
    // fwd1: h1pre = h_bf @ W1tb + b1 ; a1 = silu(LN(h1pre))
    k_gemm2<<<dim3(8, 16, 4), 256, 0, stream>>>(h_bf, 1024, W1tb, 1024, 256, 0.f, nullptr,
                                                nullptr, nullptr, 1024, Cpart, 2048, 0);
    k_red_ln_fwd<<<2048, 256, 0, stream>>>(Cpart, (size_t)2048 * 1024, 4, 1024, b1,
                                           g1, be1, mu1, r1, h1pre, a1_bf, nullptr);
    // fwd2: h2pre = a1 @ W2tb + b2 ; xout = silu(LN(h2pre))
    k_gemm2<<<dim3(2, 16, 8), 256, 0, stream>>>(a1_bf, 1024, W2tb, 1024, 128, 0.f, nullptr,
                                                nullptr, nullptr, 256, Cpart, 2048, 0);
    k_red_ln_fwd<<<2048, 256, 0, stream>>>(Cpart, (size_t)2048 * 256, 8, 256, b2,
                                           g2, be2, mu2, r2, h2pre, nullptr, xout);

    // backward
    k_ln_bwd<<<2048, 256, 0, stream>>>(nullptr, h2pre, mu2, r2, g2, be2, dh2b, 256);
    // bwd1: d_a1 = dh2b @ W2b ; dh1 = ln_bwd(d_a1) -- fused, d_a1 never materialized
    k_gemm2<<<dim3(8, 16, 4), 256, 0, stream>>>(dh2b, 256, W2b, 256, 64, 0.f, nullptr,
                                                nullptr, nullptr, 1024, Cpart, 2048, 0);
    k_red_ln_bwd<<<2048, 256, 0, stream>>>(Cpart, (size_t)2048 * 1024, 4,
                                           h1pre, mu1, r1, g1, be1, dh1b, 1024);
    gemm(dh1b, 1024, W1b, 1024, 2048, 1024, 1024, 4, sF, nullptr, nullptr, de_bf, 1024);

    // GEMM2: Gp = de @ Wsym^T. 128x256-tile, 3-buffer counted-vmcnt pipeline.
    u16* Gp = PG;   // Ppack dead after GEMM1
    k_gemm128n<<<dim3(704), 512, 0, stream>>>(de_bf, 1024, Wsym, 1024, 1024, 1.0f,
                                              Gp, NPACK);

    // y from packed symmetric Gp (shuffle-free contraction)
    k_contract_p<<<2048, 256, 0, stream>>>(Gp, t, yout);
}

// Round 11
// 419.086 us; speedup vs baseline: 1.0426x; 1.0139x over previous
//
#include <hip/hip_runtime.h>
#include <math.h>

typedef unsigned short u16;
typedef __bf16 bf16x8 __attribute__((ext_vector_type(8)));
typedef float f32x4 __attribute__((ext_vector_type(4)));

#define NPACK  11264   // padded packed-pair count (88*128)
#define NVALID 10864   // 8256 + 2080 + 528
#define BASE1  8256
#define BASE2  10336

__device__ __forceinline__ u16 f2bf(float f) {
    unsigned u = __builtin_bit_cast(unsigned, f);
    u += 0x7FFFu + ((u >> 16) & 1u);
    return (u16)(u >> 16);
}
__device__ __forceinline__ float bf2f(u16 h) {
    return __builtin_bit_cast(float, ((unsigned)h) << 16);
}

#define GLOAD_LDS16(g, l)                                                     \
    __builtin_amdgcn_global_load_lds(                                         \
        (const __attribute__((address_space(1))) void*)(g),                   \
        (__attribute__((address_space(3))) void*)(l), 16, 0, 0)

// packed triangular index (u<=v), per segment
__device__ __forceinline__ int pk0(int a, int b) {
    int u = min(a, b), v = max(a, b);
    return u * 128 - (u * (u - 1)) / 2 + (v - u);
}
__device__ __forceinline__ int pk1(int a, int b) {
    int u = min(a, b), v = max(a, b);
    return BASE1 + u * 64 - (u * (u - 1)) / 2 + (v - u);
}
__device__ __forceinline__ int pk2(int a, int b) {
    int u = min(a, b), v = max(a, b);
    return BASE2 + u * 32 - (u * (u - 1)) / 2 + (v - u);
}

// ---------------------------------------------------------------- fused prep
// bid <  86    : uv table
// 86..1109     : transpose W1 (32x32 tiles, grid 32x32)
// 1110..1365   : transpose W2 (grid 8x32)
// 1366..2389   : convert W1
// 2390..2645   : convert W2
__device__ __forceinline__ void prep_transpose(const float* __restrict__ in, int C,
                                               u16* __restrict__ out, int ldOut,
                                               int bx, int by, int tid) {
    __shared__ float tile[32][33];
    int tr0 = by * 32, tc0 = bx * 32;
    int lr = tid >> 5, lc = tid & 31;
#pragma unroll
    for (int i = 0; i < 4; i++) {
        int rr = lr + i * 8;
        tile[rr][lc] = in[(size_t)(tr0 + rr) * C + tc0 + lc];
    }
    __syncthreads();
#pragma unroll
    for (int i = 0; i < 4; i++) {
        int rr = lr + i * 8;
        out[(size_t)(tc0 + rr) * ldOut + tr0 + lc] = f2bf(tile[lc][rr]);
    }
}
__device__ __forceinline__ void prep_convert(const float* __restrict__ in,
                                             u16* __restrict__ out, int i, int n4) {
    if (i >= n4) return;
    float4 v = ((const float4*)in)[i];
    union { u16 a[4]; unsigned long long q; } o;
    o.a[0] = f2bf(v.x); o.a[1] = f2bf(v.y); o.a[2] = f2bf(v.z); o.a[3] = f2bf(v.w);
    ((unsigned long long*)out)[i] = o.q;
}

__global__ __launch_bounds__(256) void k_prep(u16* __restrict__ tab,
                                              const float* __restrict__ W1,
                                              const float* __restrict__ W2,
                                              u16* __restrict__ W1b,
                                              u16* __restrict__ W1tb,
                                              u16* __restrict__ W2b,
                                              u16* __restrict__ W2tb) {
    int bid = blockIdx.x, tid = threadIdx.x;
    if (bid < 86) {
        int j = bid * 256 + tid;
        if (j < 16384) {
            int u = j >> 7, v = j & 127;
            if (v >= u) tab[pk0(u, v)] = (u16)((u << 7) | v);
        } else if (j < 20480) {
            int k = j - 16384, u = k >> 6, v = k & 63;
            if (v >= u) tab[pk1(u, v)] = (u16)((1 << 14) | (u << 7) | v);
        } else if (j < 21504) {
            int k = j - 20480, u = k >> 5, v = k & 31;
            if (v >= u) tab[pk2(u, v)] = (u16)((2 << 14) | (u << 7) | v);
        } else if (j < 21504 + (NPACK - NVALID)) {
            tab[NVALID + (j - 21504)] = 0xFFFFu;
        }
    } else if (bid < 1110) {
        int k = bid - 86;                       // grid 32x32
        prep_transpose(W1, 1024, W1tb, 1024, k & 31, k >> 5, tid);
    } else if (bid < 1366) {
        int k = bid - 1110;                     // grid 8x32
        prep_transpose(W2, 256, W2tb, 1024, k & 7, k >> 3, tid);
    } else if (bid < 2390) {
        prep_convert(W1, W1b, (bid - 1366) * 256 + tid, 1024 * 1024 / 4);
    } else {
        prep_convert(W2, W2b, (bid - 2390) * 256 + tid, 1024 * 256 / 4);
    }
}

// ---------------------------------------------------------------- packed weights
__global__ __launch_bounds__(256) void k_packw(const float* __restrict__ w0,
                                               const float* __restrict__ w1,
                                               const float* __restrict__ w2,
                                               const u16* __restrict__ tab,
                                               u16* __restrict__ Wsym,
                                               u16* __restrict__ Wt) {
    __shared__ u16 tile[32][258];
    __shared__ u16 te[32];
    int i0 = blockIdx.x * 32, h0 = blockIdx.y * 256, tid = threadIdx.x;
    if (tid < 32) te[tid] = tab[i0 + tid];
    __syncthreads();
    const float s1 = 0.57735026918962576f, s2 = 0.44721359549995794f;
    for (int il = 0; il < 32; il++) {
        unsigned e = te[il];
        float val = 0.f;
        if ((e >> 14) != 3) {
            int seg = e >> 14, u = (e >> 7) & 127, v = e & 127;
            const float* wb; int S; float sc;
            if (seg == 0)      { wb = w0; S = 128; sc = 1.f; }
            else if (seg == 1) { wb = w1; S = 64;  sc = s1; }
            else               { wb = w2; S = 32;  sc = s2; }
            val = sc * (wb[(size_t)(u * S + v) * 1024 + h0 + tid] +
                        wb[(size_t)(v * S + u) * 1024 + h0 + tid]);
        }
        u16 bv = f2bf(val);
        Wsym[(size_t)(i0 + il) * 1024 + h0 + tid] = bv;
        tile[il][tid] = bv;
    }
    __syncthreads();
    union { u16 a[32]; uint4 q[4]; } pk;
#pragma unroll
    for (int il = 0; il < 32; il++) pk.a[il] = tile[il][tid];
    uint4* dst = (uint4*)(Wt + (size_t)(h0 + tid) * NPACK + i0);
#pragma unroll
    for (int q = 0; q < 4; q++) dst[q] = pk.q[q];
}

// ---------------------------------------------------------------- packed features
__global__ __launch_bounds__(256) void k_features_pack(const float* __restrict__ t,
                                                       const u16* __restrict__ tab,
                                                       u16* __restrict__ P) {
    __shared__ u16 tab_s[NPACK];
    __shared__ float tr[480];
    int b = blockIdx.x, tid = threadIdx.x;
    for (int j = tid; j < NPACK / 8; j += 256)
        ((uint4*)tab_s)[j] = ((const uint4*)tab)[j];
    for (int j = tid; j < 480; j += 256) tr[j] = t[(size_t)b * 480 + j];
    __syncthreads();
    u16* row = P + (size_t)b * NPACK;
    for (int i = tid; i < NPACK; i += 256) {
        unsigned e = tab_s[i];
        float p = 0.f;
        if ((e >> 14) != 3) {
            int seg = e >> 14, u = (e >> 7) & 127, v = e & 127;
            if (seg == 0) p = tr[u] * tr[v];
            else if (seg == 1) {
                const float* x1 = tr + 128;
                p = x1[u*3]*x1[v*3] + x1[u*3+1]*x1[v*3+1] + x1[u*3+2]*x1[v*3+2];
            } else {
                const float* x2 = tr + 320;
#pragma unroll
                for (int m = 0; m < 5; m++) p += x2[u*5+m] * x2[v*5+m];
            }
            if (u == v) p *= 0.5f;
        }
        row[i] = f2bf(p);
    }
}

// ---------------------------------------------------------------- GEMM 128-tile (MLP sizes)
__global__ __launch_bounds__(256) void k_gemm2(const u16* __restrict__ A, int ldA,
                                               const u16* __restrict__ B, int ldB,
                                               int kLen, float scale,
                                               const float* __restrict__ bias,
                                               float* __restrict__ Cf,
                                               u16* __restrict__ Cb, int ldC,
                                               u16* __restrict__ Cpart, int Mtot,
                                               int swz) {
    __shared__ u16 As[2][128 * 32];
    __shared__ u16 Bs[2][128 * 32];
    const int tid = threadIdx.x;
    const int wave = tid >> 6, lane = tid & 63;
    const int wm = wave >> 1, wn = wave & 1;
    int nT, mT, z;
    if (swz == 1) {
        int L = blockIdx.x;
        z = L & 7; int r = L >> 3;
        nT = r >> 4; mT = r & 15;
    } else if (swz == 2) {
        int L = blockIdx.x;
        int c = L & 7, r = L >> 3;
        nT = (r % 11) * 8 + c; mT = r / 11; z = 0;
    } else {
        nT = blockIdx.x; mT = blockIdx.y; z = blockIdx.z;
    }
    const int m0 = mT * 128, n0 = nT * 128;
    const size_t kOff = (size_t)z * kLen;

    const int chl = (((lane & 3) ^ ((lane >> 3) & 3))) * 8;
    const u16* aG = A + (size_t)(m0 + wave * 32 + (lane >> 2)) * ldA + kOff + chl;
    const u16* bG = B + (size_t)(n0 + wave * 32 + (lane >> 2)) * ldB + kOff + chl;
    const size_t aS = (size_t)16 * ldA;
    const size_t bS = (size_t)16 * ldB;
    u16* aL0 = &As[0][(wave * 32) * 32];
    u16* aL1 = &As[0][(wave * 32 + 16) * 32];
    u16* aH0 = &As[1][(wave * 32) * 32];
    u16* aH1 = &As[1][(wave * 32 + 16) * 32];
    u16* bL0 = &Bs[0][(wave * 32) * 32];
    u16* bL1 = &Bs[0][(wave * 32 + 16) * 32];
    u16* bH0 = &Bs[1][(wave * 32) * 32];
    u16* bH1 = &Bs[1][(wave * 32 + 16) * 32];

    f32x4 acc[4][4];
#pragma unroll
    for (int i = 0; i < 4; i++)
#pragma unroll
        for (int j = 0; j < 4; j++) acc[i][j] = (f32x4){0.f, 0.f, 0.f, 0.f};

    const int ml = lane & 15, kq8 = lane >> 4;
    const int kqs = (kq8 ^ ((ml >> 1) & 3)) * 8;
    const u16* aRd0 = &As[0][(wm * 64 + ml) * 32 + kqs];
    const u16* bRd0 = &Bs[0][(wn * 64 + ml) * 32 + kqs];
    const u16* aRd1 = &As[1][(wm * 64 + ml) * 32 + kqs];
    const u16* bRd1 = &Bs[1][(wn * 64 + ml) * 32 + kqs];

    for (int k = 0; k < kLen; k += 64) {
        GLOAD_LDS16(aG, aL0);
        GLOAD_LDS16(aG + aS, aL1);
        GLOAD_LDS16(aG + 32, aH0);
        GLOAD_LDS16(aG + aS + 32, aH1);
        GLOAD_LDS16(bG, bL0);
        GLOAD_LDS16(bG + bS, bL1);
        GLOAD_LDS16(bG + 32, bH0);
        GLOAD_LDS16(bG + bS + 32, bH1);
        aG += 64; bG += 64;
        __syncthreads();
        {
            bf16x8 af[4], bfv[4];
#pragma unroll
            for (int i = 0; i < 4; i++) af[i]  = *(const bf16x8*)(aRd0 + i * 16 * 32);
#pragma unroll
            for (int j = 0; j < 4; j++) bfv[j] = *(const bf16x8*)(bRd0 + j * 16 * 32);
#pragma unroll
            for (int i = 0; i < 4; i++)
#pragma unroll
                for (int j = 0; j < 4; j++)
                    acc[i][j] = __builtin_amdgcn_mfma_f32_16x16x32_bf16(af[i], bfv[j], acc[i][j], 0, 0, 0);
        }
        {
            bf16x8 af[4], bfv[4];
#pragma unroll
            for (int i = 0; i < 4; i++) af[i]  = *(const bf16x8*)(aRd1 + i * 16 * 32);
#pragma unroll
            for (int j = 0; j < 4; j++) bfv[j] = *(const bf16x8*)(bRd1 + j * 16 * 32);
#pragma unroll
            for (int i = 0; i < 4; i++)
#pragma unroll
                for (int j = 0; j < 4; j++)
                    acc[i][j] = __builtin_amdgcn_mfma_f32_16x16x32_bf16(af[i], bfv[j], acc[i][j], 0, 0, 0);
        }
        __syncthreads();
    }

    const int q = lane >> 4, nl = lane & 15;
    if (Cpart) {
        u16* outP = Cpart + (size_t)z * Mtot * ldC;
#pragma unroll
        for (int i = 0; i < 4; i++)
#pragma unroll
            for (int j = 0; j < 4; j++)
#pragma unroll
                for (int reg = 0; reg < 4; reg++) {
                    int row = m0 + wm * 64 + i * 16 + q * 4 + reg;
                    int col = n0 + wn * 64 + j * 16 + nl;
                    outP[(size_t)row * ldC + col] = f2bf(acc[i][j][reg]);
                }
    } else {
#pragma unroll
        for (int i = 0; i < 4; i++)
#pragma unroll
            for (int j = 0; j < 4; j++)
#pragma unroll
                for (int reg = 0; reg < 4; reg++) {
                    int row = m0 + wm * 64 + i * 16 + q * 4 + reg;
                    int col = n0 + wn * 64 + j * 16 + nl;
                    float v = acc[i][j][reg] * scale + (bias ? bias[col] : 0.0f);
                    if (Cf) Cf[(size_t)row * ldC + col] = v;
                    else    Cb[(size_t)row * ldC + col] = f2bf(v);
                }
    }
}

// ---------------------------------------------------------------- GEMM 256-tile (GEMM1), R3 schedule
#define VMCNT0 asm volatile("s_waitcnt vmcnt(0)" ::: "memory")
#define VMCNT6 asm volatile("s_waitcnt vmcnt(6)" ::: "memory")
#define BARX() __builtin_amdgcn_s_barrier()

#define STG_A(p, kh, rh, kb) GLOAD_LDS16(aB + (size_t)(rh) * aH + (kb) + (kh) * 32, \
                                         &As[p][kh][((rh) * 128 + wave * 16) * 32])
#define STG_B(p, kh, rh, kb) GLOAD_LDS16(bB + (size_t)(rh) * bH + (kb) + (kh) * 32, \
                                         &Bs[p][kh][((rh) * 128 + wave * 16) * 32])
#define MMQ(fb, gb, bv) do { _Pragma("unroll") \
    for (int ff = 0; ff < 4; ff++) { _Pragma("unroll") \
        for (int gg = 0; gg < 2; gg++) { \
            acc[(fb)+ff][(gb)+gg] = __builtin_amdgcn_mfma_f32_16x16x32_bf16(a[2*ff],   bv[2*gg],   acc[(fb)+ff][(gb)+gg], 0, 0, 0); \
            acc[(fb)+ff][(gb)+gg] = __builtin_amdgcn_mfma_f32_16x16x32_bf16(a[2*ff+1], bv[2*gg+1], acc[(fb)+ff][(gb)+gg], 0, 0, 0); } } } while (0)

__global__ __launch_bounds__(512, 2) void k_gemm256(const u16* __restrict__ A, int ldA,
                                                    const u16* __restrict__ B, int ldB,
                                                    int kLen, float scale,
                                                    const float* __restrict__ bias,
                                                    u16* __restrict__ Cb, int ldC,
                                                    u16* __restrict__ Cpart, int Mtot,
                                                    int swz) {
    __shared__ __align__(16) u16 As[2][2][256 * 32];   // [buf][kh][row*32+k]  64 KB
    __shared__ __align__(16) u16 Bs[2][2][256 * 32];   // 64 KB
    const int tid = threadIdx.x;
    const int lane = tid & 63, wave = tid >> 6;
    const int wm = wave >> 2, wn = wave & 3;
    int mT, nT, z;
    if (swz == 1) {
        // GEMM1: 256 blocks. XCD = z = L&7. Within XCD: nT fastest.
        z = blockIdx.x & 7; int r = blockIdx.x >> 3; nT = r & 3; mT = r >> 2;
    } else {
        int x = blockIdx.x & 7, j = blockIdx.x >> 3;
        int nti = j >> 3; mT = j & 7;
        if (nti < 5)      nT = nti * 8 + x;
        else if (x < 4)   nT = 40 + x;
        else            { nT = 40 + (x - 4); mT = (j & 7) + 4; }
        z = 0;
    }
    const int m0 = mT * 256, n0 = nT * 256;
    const size_t kOff = (size_t)z * kLen;
    const int nTi = kLen >> 6;          // K-64 tiles, >= 2

    const int chl = ((tid & 3) ^ ((tid >> 3) & 3)) * 8;
    const u16* aB = A + (size_t)(m0 + (tid >> 2)) * ldA + kOff + chl;
    const u16* bB = B + (size_t)(n0 + (tid >> 2)) * ldB + kOff + chl;
    const size_t aH = (size_t)128 * ldA;
    const size_t bH = (size_t)128 * ldB;

    const int ml = lane & 15, kq8 = lane >> 4;
    const int kqs = (kq8 ^ ((ml >> 1) & 3)) * 8;
    const int aro = (wm * 128 + ml) * 32 + kqs;
    const int bro = (wn * 64 + ml) * 32 + kqs;

    f32x4 acc[8][4];
#pragma unroll
    for (int f = 0; f < 8; f++)
#pragma unroll
        for (int g = 0; g < 4; g++) acc[f][g] = (f32x4){0.f, 0.f, 0.f, 0.f};
    bf16x8 a[8], b[4], b2[4];

    STG_A(0, 0, 0, 0); STG_A(0, 0, 1, 0); STG_A(0, 1, 0, 0); STG_A(0, 1, 1, 0);
    STG_B(0, 0, 0, 0); STG_B(0, 0, 1, 0); STG_B(0, 1, 0, 0); STG_B(0, 1, 1, 0);
    VMCNT0;
    BARX();

    for (int t = 0; t < nTi; t++) {
        const int p = t & 1, p1 = p ^ 1;
        const int kb1 = (t + 1) << 6;
        const bool s1 = (t + 1) < nTi;
        // phase 0
#pragma unroll
        for (int f = 0; f < 4; f++) {
            a[2*f]   = *(const bf16x8*)&As[p][0][aro + f * 512];
            a[2*f+1] = *(const bf16x8*)&As[p][1][aro + f * 512];
        }
#pragma unroll
        for (int g = 0; g < 2; g++) {
            b[2*g]   = *(const bf16x8*)&Bs[p][0][bro + g * 512];
            b[2*g+1] = *(const bf16x8*)&Bs[p][1][bro + g * 512];
        }
        if (s1) { STG_A(p1, 0, 0, kb1); STG_A(p1, 0, 1, kb1); }
        BARX();
        __builtin_amdgcn_s_setprio(1);
        MMQ(0, 0, b);
        __builtin_amdgcn_s_setprio(0);
        BARX();
        // phase 1
#pragma unroll
        for (int g = 0; g < 2; g++) {
            b2[2*g]   = *(const bf16x8*)&Bs[p][0][bro + (g + 2) * 512];
            b2[2*g+1] = *(const bf16x8*)&Bs[p][1][bro + (g + 2) * 512];
        }
        if (s1) { STG_A(p1, 1, 0, kb1); STG_A(p1, 1, 1, kb1); }
        BARX();
        __builtin_amdgcn_s_setprio(1);
        MMQ(0, 2, b2);
        __builtin_amdgcn_s_setprio(0);
        BARX();
        // phase 2
#pragma unroll
        for (int f = 0; f < 4; f++) {
            a[2*f]   = *(const bf16x8*)&As[p][0][aro + (f + 4) * 512];
            a[2*f+1] = *(const bf16x8*)&As[p][1][aro + (f + 4) * 512];
        }
        if (s1) { STG_B(p1, 0, 0, kb1); STG_B(p1, 0, 1, kb1); }
        BARX();
        __builtin_amdgcn_s_setprio(1);
        MMQ(4, 0, b);
        __builtin_amdgcn_s_setprio(0);
        BARX();
        // phase 3
        if (s1) { STG_B(p1, 1, 0, kb1); STG_B(p1, 1, 1, kb1); }
        __builtin_amdgcn_s_setprio(1);
        MMQ(4, 2, b2);
        __builtin_amdgcn_s_setprio(0);
        if (s1) VMCNT0;
        BARX();
    }

    const int q = lane >> 4, nl = lane & 15;
    if (Cpart) {
        u16* outP = Cpart + (size_t)z * Mtot * ldC;
#pragma unroll
        for (int f = 0; f < 8; f++)
#pragma unroll
            for (int g = 0; g < 4; g++)
#pragma unroll
                for (int reg = 0; reg < 4; reg++) {
                    int row = m0 + wm * 128 + f * 16 + q * 4 + reg;
                    int col = n0 + wn * 64 + g * 16 + nl;
                    outP[(size_t)row * ldC + col] = f2bf(acc[f][g][reg]);
                }
    } else {
#pragma unroll
        for (int f = 0; f < 8; f++)
#pragma unroll
            for (int g = 0; g < 4; g++)
#pragma unroll
                for (int reg = 0; reg < 4; reg++) {
                    int row = m0 + wm * 128 + f * 16 + q * 4 + reg;
                    int col = n0 + wn * 64 + g * 16 + nl;
                    float v = acc[f][g][reg] * scale + (bias ? bias[col] : 0.0f);
                    Cb[(size_t)row * ldC + col] = f2bf(v);
                }
    }
}

// ---------------------------------------------------------------- GEMM 128x256-tile (GEMM2)
// R9 3-buffer counted-vmcnt skeleton + register-pipelined fragment reads:
// quadrant k+1's ds_reads issue BEFORE quadrant k's MFMA (separate aL/aH/b/b2
// register sets). ds_reads cannot sink across s_barrier; the compiler's
// counted lgkm waits then drain q1/q2 reads UNDER q0/q1's MFMA. Only ph0's
// 8 reads stay on the critical path. Barriers/stages/vmcnt unchanged vs R9.
#define MMQ22(fb, gb, av, bv) do { _Pragma("unroll") \
    for (int ff = 0; ff < 2; ff++) { _Pragma("unroll") \
        for (int gg = 0; gg < 2; gg++) { \
            acc[(fb)+ff][(gb)+gg] = __builtin_amdgcn_mfma_f32_16x16x32_bf16(av[2*ff],   bv[2*gg],   acc[(fb)+ff][(gb)+gg], 0, 0, 0); \
            acc[(fb)+ff][(gb)+gg] = __builtin_amdgcn_mfma_f32_16x16x32_bf16(av[2*ff+1], bv[2*gg+1], acc[(fb)+ff][(gb)+gg], 0, 0, 0); } } } while (0)

__global__ __launch_bounds__(512, 2) void k_gemm128n(const u16* __restrict__ A, int ldA,
                                                     const u16* __restrict__ B, int ldB,
                                                     int kLen, float scale,
                                                     u16* __restrict__ Cb, int ldC) {
    __shared__ __align__(16) u16 As[3][2][128 * 32];   // 48 KB
    __shared__ __align__(16) u16 Bs[3][2][256 * 32];   // 96 KB
    const int tid = threadIdx.x;
    const int lane = tid & 63, wave = tid >> 6;
    const int wm = wave >> 2, wn = wave & 3;           // wm 0..1, wn 0..3
    int x = blockIdx.x & 7, j = blockIdx.x >> 3;
    int nti = j >> 4, mT = j & 15, nT;
    if (nti < 5) nT = nti * 8 + x;
    else { nT = 40 + (x & 3); mT = (j & 7) + 8 * (x >> 2); }
    const int m0 = mT * 128, n0 = nT * 256;
    const int nTi = kLen >> 6;

    const int chl = ((tid & 3) ^ ((tid >> 3) & 3)) * 8;
    const u16* aB = A + (size_t)(m0 + (tid >> 2)) * ldA + chl;   // rows 0..127
    const u16* bB = B + (size_t)(n0 + (tid >> 2)) * ldB + chl;
    const size_t bH = (size_t)128 * ldB;

    const int ml = lane & 15, kq8 = lane >> 4;
    const int kqs = (kq8 ^ ((ml >> 1) & 3)) * 8;
    const int aro = (wm * 64 + ml) * 32 + kqs;
    const int bro = (wn * 64 + ml) * 32 + kqs;

    f32x4 acc[4][4];
#pragma unroll
    for (int f = 0; f < 4; f++)
#pragma unroll
        for (int g = 0; g < 4; g++) acc[f][g] = (f32x4){0.f, 0.f, 0.f, 0.f};
    bf16x8 aL[4], aHr[4], b[4], b2[4];

#define SG_A(p, kh, kb) GLOAD_LDS16(aB + (kb) + (kh) * 32, &As[p][kh][(wave * 16) * 32])
#define SG_B(p, kh, rh, kb) GLOAD_LDS16(bB + (size_t)(rh) * bH + (kb) + (kh) * 32, \
                                        &Bs[p][kh][((rh) * 128 + wave * 16) * 32])

    // prologue: stage T0 -> buf0 (6) and T1 -> buf1 (6); retire T0; barrier.
    SG_A(0, 0, 0); SG_A(0, 1, 0);
    SG_B(0, 0, 0, 0); SG_B(0, 0, 1, 0); SG_B(0, 1, 0, 0); SG_B(0, 1, 1, 0);
    if (nTi > 1) {
        SG_A(1, 0, 64); SG_A(1, 1, 64);
        SG_B(1, 0, 0, 64); SG_B(1, 0, 1, 64); SG_B(1, 1, 0, 64); SG_B(1, 1, 1, 64);
        VMCNT6;
    } else {
        VMCNT0;
    }
    BARX();

    int p = 0;
    for (int t = 0; t < nTi; t++) {
        const int p2 = (p >= 1) ? p - 1 : 2;           // (t+2) % 3
        const int kb2 = (t + 2) << 6;
        const bool s2 = (t + 2) < nTi;
        const bool s1 = (t + 1) < nTi;
        // phase 0: read q0 (aL,b) + PREFETCH q1 (b2); stage t+2 A kh0+kh1
#pragma unroll
        for (int f = 0; f < 2; f++) {
            aL[2*f]   = *(const bf16x8*)&As[p][0][aro + f * 512];
            aL[2*f+1] = *(const bf16x8*)&As[p][1][aro + f * 512];
        }
#pragma unroll
        for (int g = 0; g < 2; g++) {
            b[2*g]   = *(const bf16x8*)&Bs[p][0][bro + g * 512];
            b[2*g+1] = *(const bf16x8*)&Bs[p][1][bro + g * 512];
        }
#pragma unroll
        for (int g = 0; g < 2; g++) {
            b2[2*g]   = *(const bf16x8*)&Bs[p][0][bro + (g + 2) * 512];
            b2[2*g+1] = *(const bf16x8*)&Bs[p][1][bro + (g + 2) * 512];
        }
        if (s2) { SG_A(p2, 0, kb2); SG_A(p2, 1, kb2); }
        BARX();
        __builtin_amdgcn_s_setprio(1);
        MMQ22(0, 0, aL, b);                    // waits aL,b; b2 drains under it
        __builtin_amdgcn_s_setprio(0);
        BARX();
        // phase 1: PREFETCH q2 (aH); stage t+2 B kh0
#pragma unroll
        for (int f = 0; f < 2; f++) {
            aHr[2*f]   = *(const bf16x8*)&As[p][0][aro + (f + 2) * 512];
            aHr[2*f+1] = *(const bf16x8*)&As[p][1][aro + (f + 2) * 512];
        }
        if (s2) { SG_B(p2, 0, 0, kb2); SG_B(p2, 0, 1, kb2); }
        BARX();
        __builtin_amdgcn_s_setprio(1);
        MMQ22(0, 2, aL, b2);                   // b2 ready; aH drains under it
        __builtin_amdgcn_s_setprio(0);
        BARX();
        // phase 2: no new reads; stage t+2 B kh1
        if (s2) { SG_B(p2, 1, 0, kb2); SG_B(p2, 1, 1, kb2); }
        BARX();
        __builtin_amdgcn_s_setprio(1);
        MMQ22(2, 0, aHr, b);
        __builtin_amdgcn_s_setprio(0);
        BARX();
        // phase 3: all regs held; counted boundary wait
        __builtin_amdgcn_s_setprio(1);
        MMQ22(2, 2, aHr, b2);
        __builtin_amdgcn_s_setprio(0);
        if (s2)      { VMCNT6; }   // retire t+1's 6 (old); t+2's 6 stay in flight
        else if (s1) { VMCNT0; }   // tail: only t+1's (old) loads outstanding
        BARX();
        p = (p == 2) ? 0 : p + 1;
    }

    const int q = lane >> 4, nl = lane & 15;
#pragma unroll
    for (int f = 0; f < 4; f++)
#pragma unroll
        for (int g = 0; g < 4; g++)
#pragma unroll
            for (int reg = 0; reg < 4; reg++) {
                int row = m0 + wm * 64 + f * 16 + q * 4 + reg;
                int col = n0 + wn * 64 + g * 16 + nl;
                Cb[(size_t)row * ldC + col] = f2bf(acc[f][g][reg] * scale);
            }
}

// sum split-K bf16 partials + epilogue
__global__ __launch_bounds__(256) void k_reduce(const u16* __restrict__ part, size_t stride,
                                                int SK, int total, int N, float scale,
                                                const float* __restrict__ bias,
                                                float* __restrict__ outF, u16* __restrict__ outB) {
    int i = blockIdx.x * 256 + threadIdx.x;
    if (i >= total) return;
    float s = 0.f;
    for (int z = 0; z < SK; z++) s += bf2f(part[(size_t)z * stride + i]);
    float v = s * scale + (bias ? bias[i % N] : 0.0f);
    if (outF) outF[i] = v;
    else      outB[i] = f2bf(v);
}

// ---------------------------------------------------------------- rowwise LN
__device__ __forceinline__ float blockReduce(float v, float* red) {
#pragma unroll
    for (int off = 32; off > 0; off >>= 1) v += __shfl_down(v, off);
    __syncthreads();
    if ((threadIdx.x & 63) == 0) red[threadIdx.x >> 6] = v;
    __syncthreads();
    return red[0] + red[1] + red[2] + red[3];
}

// Fused: split-K reduce + bias -> pre (stored f32 for bwd) -> LN + SiLU.
// One block per row; D in {256, 1024}; SK partials are bf16.
__global__ __launch_bounds__(256) void k_red_ln_fwd(const u16* __restrict__ part,
    size_t stride, int SK, int D,
    const float* __restrict__ bias,
    const float* __restrict__ g, const float* __restrict__ be,
    float* __restrict__ mu_out, float* __restrict__ r_out,
    float* __restrict__ pre_out,
    u16* __restrict__ a_bf, float* __restrict__ a_f32) {
    __shared__ float red[4];
    int b = blockIdx.x, tid = threadIdx.x;
    int nd = D >> 8;
    float v_[4];
    float s = 0.f, s2 = 0.f;
    for (int r = 0; r < nd; r++) {
        int i = tid + (r << 8);
        size_t idx = (size_t)b * D + i;
        float v = 0.f;
        for (int z = 0; z < SK; z++) v += bf2f(part[(size_t)z * stride + idx]);
        v += bias[i];
        v_[r] = v;
        pre_out[idx] = v;
        s += v; s2 += v * v;
    }
    s = blockReduce(s, red);
    s2 = blockReduce(s2, red);
    float mu = s / D;
    float var = s2 / D - mu * mu;
    float rst = rsqrtf(var + 1e-6f);
    if (tid == 0) { mu_out[b] = mu; r_out[b] = rst; }
    for (int r = 0; r < nd; r++) {
        int i = tid + (r << 8);
        float xh = (v_[r] - mu) * rst;
        float ln = xh * g[i] + be[i];
        float a = ln / (1.0f + expf(-ln));
        if (a_bf)  a_bf[(size_t)b * D + i] = f2bf(a);
        if (a_f32) a_f32[(size_t)b * D + i] = a;
    }
}

// Fused layer-2: split-K reduce + bias -> LN -> SiLU -> xout AND LN-backward
// with dup==1 -> dh2b. h2pre/mu2/r2 never materialize (D = 256 = blockDim).
__global__ __launch_bounds__(256) void k_red_ln_fb2(const u16* __restrict__ part,
    size_t stride, int SK,
    const float* __restrict__ bias,
    const float* __restrict__ g, const float* __restrict__ be,
    float* __restrict__ xout, u16* __restrict__ dh_bf) {
    __shared__ float red[4];
    int b = blockIdx.x, i = threadIdx.x;
    size_t idx = (size_t)b * 256 + i;
    float v = 0.f;
    for (int z = 0; z < SK; z++) v += bf2f(part[(size_t)z * stride + idx]);
    v += bias[i];
    float s  = blockReduce(v, red);
    float s2 = blockReduce(v * v, red);
    float mu = s / 256;
    float var = s2 / 256 - mu * mu;
    float rst = rsqrtf(var + 1e-6f);
    float xh = (v - mu) * rst;
    float ln = xh * g[i] + be[i];
    float sg = 1.0f / (1.0f + expf(-ln));
    xout[idx] = ln * sg;                       // silu(LN)
    float dsilu = sg * (1.0f + ln * (1.0f - sg));
    float w = g[i] * dsilu;                    // dup == 1
    float sw  = blockReduce(w, red);
    float swx = blockReduce(w * xh, red);
    float invD = 1.0f / 256.0f;
    float dx = rst * (w - sw * invD - xh * swx * invD);
    dh_bf[idx] = f2bf(dx);
}

// Fused: split-K reduce (upstream grad, no bias) + LN backward.
__global__ __launch_bounds__(256) void k_red_ln_bwd(const u16* __restrict__ part,
    size_t stride, int SK,
    const float* __restrict__ X, const float* __restrict__ mu_in, const float* __restrict__ r_in,
    const float* __restrict__ g, const float* __restrict__ be,
    u16* __restrict__ out_bf, int D) {
    __shared__ float red[4];
    int b = blockIdx.x, tid = threadIdx.x;
    const float* x = X + (size_t)b * D;
    float mu = mu_in[b], rst = r_in[b];
    int nd = D >> 8;
    float w_[4], xh_[4];
    float sw = 0.f, swx = 0.f;
    for (int r = 0; r < nd; r++) {
        int i = tid + (r << 8);
        size_t idx = (size_t)b * D + i;
        float d = 0.f;
        for (int z = 0; z < SK; z++) d += bf2f(part[(size_t)z * stride + idx]);
        float xh = (x[i] - mu) * rst;
        float ln = xh * g[i] + be[i];
        float sg = 1.0f / (1.0f + expf(-ln));
        float dsilu = sg * (1.0f + ln * (1.0f - sg));
        float w = g[i] * dsilu * d;
        w_[r] = w; xh_[r] = xh;
        sw += w; swx += w * xh;
    }
    sw = blockReduce(sw, red);
    swx = blockReduce(swx, red);
    float invD = 1.0f / D;
    for (int r = 0; r < nd; r++) {
        int i = tid + (r << 8);
        float dx = rst * (w_[r] - sw * invD - xh_[r] * swx * invD);
        out_bf[(size_t)b * D + i] = f2bf(dx);
    }
}

// ---------------------------------------------------------------- packed contraction
// y[b,a] = sum_v Gsym[a,v] x[v]. Shuffle-free: per-thread-owned outputs with
// serial accumulation over a v-range + one small LDS combine per segment.
__global__ __launch_bounds__(256) void k_contract_p(const u16* __restrict__ Gp,
                                                    const float* __restrict__ t,
                                                    float* __restrict__ y) {
    __shared__ u16 gp_s[NPACK];
    __shared__ float xs[480];
    __shared__ float red[1280];
    int b = blockIdx.x, tid = threadIdx.x;
    const uint4* gsrc = (const uint4*)(Gp + (size_t)b * NPACK);
    for (int j = tid; j < NPACK / 8; j += 256) ((uint4*)gp_s)[j] = gsrc[j];
    for (int j = tid; j < 480; j += 256) xs[j] = t[(size_t)b * 480 + j];
    __syncthreads();
    float* yr = y + (size_t)b * 480;

    // seg0: 128 outputs x 128 terms. thread = (u, half): 64 MACs, 2-way combine.
    {
        int u = tid & 127, half = tid >> 7;
        int v0 = half * 64;
        float s = 0.f;
#pragma unroll 8
        for (int i = 0; i < 64; i++) {
            int v = v0 + i;
            s += bf2f(gp_s[pk0(u, v)]) * xs[v];
        }
        red[tid] = s;
    }
    __syncthreads();
    if (tid < 128) yr[tid] = red[tid] + red[tid + 128];
    __syncthreads();

    // seg1: 64 outputs x 3 m x 64 terms. thread = (u, q): 16 v, 4-way combine.
    {
        int u = tid & 63, q = tid >> 6;
        int v0 = q * 16;
        float a0 = 0.f, a1 = 0.f, a2 = 0.f;
#pragma unroll 4
        for (int i = 0; i < 16; i++) {
            int v = v0 + i;
            float gv = bf2f(gp_s[pk1(u, v)]);
            a0 += gv * xs[128 + v * 3 + 0];
            a1 += gv * xs[128 + v * 3 + 1];
            a2 += gv * xs[128 + v * 3 + 2];
        }
        int base = (u * 4 + q) * 3;
        red[base + 0] = a0; red[base + 1] = a1; red[base + 2] = a2;
    }
    __syncthreads();
    if (tid < 192) {
        int u = tid / 3, m = tid - u * 3;
        float s = 0.f;
#pragma unroll
        for (int q = 0; q < 4; q++) s += red[(u * 4 + q) * 3 + m];
        yr[128 + u * 3 + m] = s;
    }
    __syncthreads();

    // seg2: 32 outputs x 5 m x 32 terms. thread = (u, o): 4 v, 8-way combine.
    {
        int u = tid & 31, o = tid >> 5;
        int v0 = o * 4;
        float a[5] = {0.f, 0.f, 0.f, 0.f, 0.f};
#pragma unroll
        for (int i = 0; i < 4; i++) {
            int v = v0 + i;
            float gv = bf2f(gp_s[pk2(u, v)]);
#pragma unroll
            for (int m = 0; m < 5; m++) a[m] += gv * xs[320 + v * 5 + m];
        }
        int base = (u * 8 + o) * 5;
#pragma unroll
        for (int m = 0; m < 5; m++) red[base + m] = a[m];
    }
    __syncthreads();
    if (tid < 160) {
        int u = tid / 5, m = tid - u * 5;
        float s = 0.f;
#pragma unroll
        for (int o = 0; o < 8; o++) s += red[(u * 8 + o) * 5 + m];
        yr[320 + u * 5 + m] = s;
    }
}

// ---------------------------------------------------------------- launch
extern "C" void kernel_launch(void* const* d_in, const int* in_sizes, int n_in,
                              void* d_out, int out_size, void* d_ws, size_t ws_size,
                              hipStream_t stream) {
    const float* t   = (const float*)d_in[0];
    const float* w0  = (const float*)d_in[1];
    const float* w1  = (const float*)d_in[2];
    const float* w2  = (const float*)d_in[3];
    const float* W1  = (const float*)d_in[4];
    const float* b1  = (const float*)d_in[5];
    const float* g1  = (const float*)d_in[6];
    const float* be1 = (const float*)d_in[7];
    const float* W2  = (const float*)d_in[8];
    const float* b2  = (const float*)d_in[9];
    const float* g2  = (const float*)d_in[10];
    const float* be2 = (const float*)d_in[11];

    float* xout = (float*)d_out;                    // 2048*256
    float* yout = xout + (size_t)2048 * 256;        // 2048*480

    char* ws = (char*)d_ws;
    size_t off = 0;
    auto alloc = [&](size_t bytes) -> void* {
        void* p = ws + off;
        off += (bytes + 255) & ~(size_t)255;
        return p;
    };
    u16*   PG    = (u16*)alloc((size_t)2048 * NPACK * 2);   // Ppack, later Gp (aliased)
    u16*   Wsym  = (u16*)alloc((size_t)NPACK * 1024 * 2);   // packed Wsym [i,h]
    u16*   Wt    = (u16*)alloc((size_t)1024 * NPACK * 2);   // packed Wsym^T [h,i]
    u16*   uvtab = (u16*)alloc((size_t)NPACK * 2);
    u16*   W1b   = (u16*)alloc((size_t)1024 * 1024 * 2);
    u16*   W1tb  = (u16*)alloc((size_t)1024 * 1024 * 2);
    u16*   W2b   = (u16*)alloc((size_t)1024 * 256 * 2);
    u16*   W2tb  = (u16*)alloc((size_t)256 * 1024 * 2);
    u16*   h_bf  = (u16*)alloc((size_t)2048 * 1024 * 2);
    float* h1pre = (float*)alloc((size_t)2048 * 1024 * 4);
    float* mu1   = (float*)alloc(2048 * 4);
    float* r1    = (float*)alloc(2048 * 4);
    u16*   a1_bf = (u16*)alloc((size_t)2048 * 1024 * 2);
    u16*   dh2b  = (u16*)alloc((size_t)2048 * 256 * 2);
    u16*   dh1b  = (u16*)alloc((size_t)2048 * 1024 * 2);
    u16*   de_bf = (u16*)alloc((size_t)2048 * 1024 * 2);
    u16*   Cpart = (u16*)(ws + off);
    size_t cpartBytes = (ws_size > off) ? (ws_size - off) : 0;
    (void)in_sizes; (void)n_in; (void)out_size;

    const float sF = 1.0f / sqrtf(21504.0f);

    // generic GEMM helper: 3-D grid, optional split-K (bf16 partials)
    auto gemm = [&](const u16* A, int ldA, const u16* B, int ldB, int M, int N, int K,
                    int SKwant, float scale, const float* bias,
                    float* Cf, u16* Cb, int ldC) {
        int SK = SKwant;
        size_t slice = (size_t)M * ldC * 2;
        if (SK > 1 && cpartBytes < 2 * slice) SK = 1;
        if (SK > 1 && (size_t)SK * slice > cpartBytes) SK = (int)(cpartBytes / slice);
        while (SK > 1 && !((K % SK) == 0 && ((K / SK) % 64) == 0)) SK--;
        dim3 grid(N / 128, M / 128, SK);
        if (SK > 1) {
            k_gemm2<<<grid, 256, 0, stream>>>(A, ldA, B, ldB, K / SK, 0.f, nullptr,
                                              nullptr, nullptr, ldC, Cpart, M, 0);
            int total = M * ldC;
            k_reduce<<<(total + 255) / 256, 256, 0, stream>>>(Cpart, (size_t)M * ldC, SK,
                                                              total, N, scale, bias, Cf, Cb);
        } else {
            k_gemm2<<<grid, 256, 0, stream>>>(A, ldA, B, ldB, K, scale, bias,
                                              Cf, Cb, ldC, nullptr, M, 0);
        }
    };

    // fused prep: uv table + W transposes + W converts (one launch)
    k_prep<<<2646, 256, 0, stream>>>(uvtab, W1, W2, W1b, W1tb, W2b, W2tb);
    // packed weights (needs uvtab)
    k_packw<<<dim3(NPACK / 32, 4), 256, 0, stream>>>(w0, w1, w2, uvtab, Wsym, Wt);

    // packed features
    k_features_pack<<<2048, 256, 0, stream>>>(t, uvtab, PG);

    // GEMM1: h = sF * Ppack @ Wt^T. 256-tile: 8z x (4nT x 8mT) = 256 blocks, kLen=1408.
    k_gemm256<<<dim3(256), 512, 0, stream>>>(PG, NPACK, Wt, NPACK, NPACK / 8, 0.f, nullptr,
                                             nullptr, 1024, Cpart, 2048, 1);
    {
        int total = 2048 * 1024;
        k_reduce<<<(total + 255) / 256, 256, 0, stream>>>(Cpart, (size_t)2048 * 1024, 8,
                                                          total, 1024, sF, nullptr,
                                                          nullptr, h_bf);
    }

    // MLP forward, fused reduce+LN
    // fwd1: h1pre = h_bf @ W1tb + b1 ; a1 = silu(LN(h1pre))
    k_gemm2<<<dim3(8, 16, 4), 256, 0, stream>>>(h_bf, 1024, W1tb, 1024, 256, 0.f, nullptr,
                                                nullptr, nullptr, 1024, Cpart, 2048, 0);
    k_red_ln_fwd<<<2048, 256, 0, stream>>>(Cpart, (size_t)2048 * 1024, 4, 1024, b1,
                                           g1, be1, mu1, r1, h1pre, a1_bf, nullptr);
    // fwd2 + start of backward, fully fused: xout = silu(LN(pre2)), dh2b = ln_bwd(1)
    k_gemm2<<<dim3(2, 16, 8), 256, 0, stream>>>(a1_bf, 1024, W2tb, 1024, 128, 0.f, nullptr,
                                                nullptr, nullptr, 256, Cpart, 2048, 0);
    k_red_ln_fb2<<<2048, 256, 0, stream>>>(Cpart, (size_t)2048 * 256, 8, b2,
                                           g2, be2, xout, dh2b);

    // backward
    // bwd1: d_a1 = dh2b @ W2b ; dh1 = ln_bwd(d_a1) -- fused, d_a1 never materialized
    k_gemm2<<<dim3(8, 16, 4), 256, 0, stream>>>(dh2b, 256, W2b, 256, 64, 0.f, nullptr,
                                                nullptr, nullptr, 1024, Cpart, 2048, 0);
    k_red_ln_bwd<<<2048, 256, 0, stream>>>(Cpart, (size_t)2048 * 1024, 4,
                                           h1pre, mu1, r1, g1, be1, dh1b, 1024);
    gemm(dh1b, 1024, W1b, 1024, 2048, 1024, 1024, 4, sF, nullptr, nullptr, de_bf, 1024);

    // GEMM2: Gp = de @ Wsym^T. 128x256-tile, 3-buffer pipeline + reg-prefetch reads.
    u16* Gp = PG;   // Ppack dead after GEMM1
    k_gemm128n<<<dim3(704), 512, 0, stream>>>(de_bf, 1024, Wsym, 1024, 1024, 1.0f,
                                              Gp, NPACK);

    // y from packed symmetric Gp (shuffle-free contraction)
    k_contract_p<<<2048, 256, 0, stream>>>(Gp, t, yout);
}